// Round 3
// baseline (442.349 us; speedup 1.0000x reference)
//
#include <hip/hip_runtime.h>

// ---------------------------------------------------------------------------
// QuantizedAttention: x[B,S,D] -> QKV proj (int8-quant wts) -> RMSNorm -> RoPE
//   -> causal GQA attention -> O proj.  B=2 S=2048 D=2048 H=16 KVH=8 HD=128.
// R10: GEMM core rebuilt as m97-style LDS-staged loop (global_load_lds into
// double-buffered 16KB fragment tiles; each fragment loaded ONCE per block;
// staging registers eliminated -> occupancy 1 -> 4 blocks/CU) + XCD-strip
// block swizzle (per-XCD B-slab 2MB L2-resident).  attn unchanged from R9.
// ---------------------------------------------------------------------------

typedef __attribute__((ext_vector_type(4))) float floatx4;
typedef __attribute__((ext_vector_type(8))) short short8v;
typedef __attribute__((ext_vector_type(4))) short short4v;
typedef __attribute__((ext_vector_type(8))) unsigned short ushort8v;

#define DEVINL __device__ __forceinline__

constexpr int cB = 2, cS = 2048, cD = 2048, cH = 16, cKVH = 8, cHD = 128;
constexpr int cM = cB * cS;
constexpr int cNqkv = (cH + 2 * cKVH) * cHD;
constexpr float cEPS = 1e-6f;
// 1/sqrt(HD) * log2(e): softmax in base-2 domain (same softmax value).
constexpr float cSCL2 = 0.08838834764831845f * 1.4426950408889634f;

DEVINL unsigned short f2bf(float f) {
  unsigned u = __float_as_uint(f);
  unsigned r = ((u >> 16) & 1u) + 0x7FFFu;
  return (unsigned short)((u + r) >> 16);
}
DEVINL float bf2f(unsigned short h) { return __uint_as_float(((unsigned)h) << 16); }

DEVINL floatx4 mfma_bf16(short8v a, short8v b, floatx4 c) {
  return __builtin_amdgcn_mfma_f32_16x16x32_bf16(a, b, c, 0, 0, 0);
}

DEVINL void gl_lds16(const void* g, void* l) {
  __builtin_amdgcn_global_load_lds(
      (const __attribute__((address_space(1))) void*)g,
      (__attribute__((address_space(3))) void*)l, 16, 0, 0);
}

// --------------------------- dtype detection -------------------------------
__global__ void detect_dtype(const unsigned* __restrict__ x, int* __restrict__ flag) {
  __shared__ int cnt;
  if (threadIdx.x == 0) cnt = 0;
  __syncthreads();
  int c = 0;
  for (int i = threadIdx.x; i < 4096; i += 256) {
    unsigned e = (x[i] >> 7) & 0xFFu;
    c += (e >= 100u && e <= 142u) ? 1 : 0;
  }
  atomicAdd(&cnt, c);
  __syncthreads();
  if (threadIdx.x == 0) *flag = (cnt > 2457) ? 1 : 0;  // 1 = host is bf16
}

// --------------------------- merged small conversions ----------------------
__global__ void conv_small(const void* p9, const void* p10, const void* p2,
                           const void* p4, const void* p6, const void* p8,
                           float* __restrict__ nw, float* __restrict__ scat,
                           float* __restrict__ so, const int* __restrict__ flag) {
  int i = blockIdx.x * 256 + threadIdx.x;
  int f = *flag;
  auto rd = [&](const void* p, int idx) -> float {
    return f ? bf2f(((const unsigned short*)p)[idx]) : ((const float*)p)[idx];
  };
  if (i < 256) {
    nw[i] = (i < 128) ? rd(p9, i) : rd(p10, i - 128);
  } else if (i < 256 + 4096) {
    int j = i - 256;
    scat[j] = (j < 2048) ? rd(p2, j) : (j < 3072 ? rd(p4, j - 2048) : rd(p6, j - 3072));
  } else if (i < 256 + 4096 + 2048) {
    int j = i - 4352;
    so[j] = rd(p8, j);
  }
}

// Packed RoPE table: tab[s*64+t] = {cos[s,t], sin[s,t]} (halves equal).
__global__ void rope_pack(const void* __restrict__ cosc, const void* __restrict__ sinc,
                          float2* __restrict__ tab, const int* __restrict__ flag) {
  int i = blockIdx.x * 256 + threadIdx.x;
  if (i >= cS * 64) return;
  int s = i >> 6, t = i & 63;
  int f = *flag;
  float c = f ? bf2f(((const unsigned short*)cosc)[s * cHD + t])
              : ((const float*)cosc)[s * cHD + t];
  float sn = f ? bf2f(((const unsigned short*)sinc)[s * cHD + t])
               : ((const float*)sinc)[s * cHD + t];
  tab[i] = make_float2(c, sn);
}

// --------------------------- fragment packers ------------------------------
// Fragment layout: dst[(T*64 + kb)*512 + lane*8 + j] =
//   src[T*16 + (lane&15)][kb*32 + (lane>>4)*8 + j]
DEVINL void pack_body(const void* src, unsigned short* dst, int K, int md,
                      int Trow, int Tdst, int kc, int tid, float L[16][264]) {
#pragma unroll
  for (int it = 0; it < 16; it++) {
    int e = it * 256 + tid;
    int r = e >> 8, c = e & 255;
    size_t idx = (size_t)(Trow * 16 + r) * K + kc * 256 + c;
    float v;
    if (md == 1)      v = ((const float*)src)[idx];
    else if (md == 2) v = (float)((const int*)src)[idx];
    else              v = bf2f(((const unsigned short*)src)[idx]);
    L[r][c] = v;
  }
  __syncthreads();
  const int lane = tid & 63, w = tid >> 6;
  const int q = lane >> 4, l16 = lane & 15;
#pragma unroll
  for (int p = 0; p < 2; p++) {
    int kbl = w + p * 4;
    ushort8v o;
#pragma unroll
    for (int j = 0; j < 8; j++) o[j] = f2bf(L[l16][kbl * 32 + q * 8 + j]);
    *(ushort8v*)(dst + ((size_t)Tdst * 64 + kc * 8 + kbl) * 512 + lane * 8) = o;
  }
}

__global__ __launch_bounds__(256) void pack_frag(
    const void* __restrict__ src, unsigned short* __restrict__ dst,
    int K, int mode, const int* __restrict__ flag) {
  __shared__ float L[16][264];
  int md = mode;
  if (md == 0) md = (*flag) ? 3 : 1;
  pack_body(src, dst, K, md, blockIdx.x, blockIdx.x, blockIdx.y, threadIdx.x, L);
}

// All three QKV weight tensors in one dispatch (T: 0..127 wq, 128..191 wk,
// 192..255 wv); dst layout continuous in T (matches gemm_qkv's Bp).
__global__ __launch_bounds__(256) void pack_wqkv(
    const int* __restrict__ wq, const int* __restrict__ wk,
    const int* __restrict__ wv, unsigned short* __restrict__ dst) {
  __shared__ float L[16][264];
  int T = blockIdx.x;
  const int* src;
  int Trow;
  if (T < 128)      { src = wq; Trow = T; }
  else if (T < 192) { src = wk; Trow = T - 128; }
  else              { src = wv; Trow = T - 192; }
  pack_body(src, dst, 2048, 2, Trow, T, blockIdx.y, threadIdx.x, L);
}

// --------------------- LDS-staged GEMM core (m97 structure) ----------------
// Block 128x128, 4 waves (2x2 of 64x64).  Per K-step (32): 16 fragment tile
// slices (8 A + 8 B, 1KB each) staged once via global_load_lds into a 16KB
// buffer (double-buffered, 32KB).  Fragment-packed layout => LDS dest linear
// (wave-uniform base + lane*16) and ds_read_b128 conflict-free.
// SM must point at >= 16384 ushorts (32KB).
DEVINL void gemm_core(const unsigned short* __restrict__ Ap,
                      const unsigned short* __restrict__ Bp,
                      unsigned short* __restrict__ SM,
                      int tmB, int tnB, int nkb, int tid,
                      floatx4 acc[4][4]) {
  const int lane = tid & 63, wv = tid >> 6;
  // staging sources: load i covers tile t = i*4+wv (t<8: A tile, else B tile)
  const unsigned short* g[4];
#pragma unroll
  for (int i = 0; i < 4; i++) {
    int t = i * 4 + wv;
    g[i] = (t < 8 ? Ap + ((size_t)(tmB + t) * 64) * 512
                  : Bp + ((size_t)(tnB + t - 8) * 64) * 512) + lane * 8;
  }
  const int at0 = (wv & 1) * 4, bt0 = 8 + (wv >> 1) * 4;

  // stage K-step kb into buffer (kb&1)
  auto stage = [&](int kb) {
    unsigned short* buf = SM + (kb & 1) * 8192;
#pragma unroll
    for (int i = 0; i < 4; i++)
      gl_lds16(g[i] + (size_t)kb * 512, buf + (i * 4 + wv) * 512 + lane * 8);
  };

  stage(0);
  for (int kb = 0; kb < nkb; kb++) {
    __syncthreads();                       // staged(kb) visible; buf^1 free
    if (kb + 1 < nkb) stage(kb + 1);
    const unsigned short* buf = SM + (kb & 1) * 8192;
    short8v a[4], b[4];
#pragma unroll
    for (int mt = 0; mt < 4; mt++)
      a[mt] = *(const short8v*)(buf + (at0 + mt) * 512 + lane * 8);
#pragma unroll
    for (int nt = 0; nt < 4; nt++)
      b[nt] = *(const short8v*)(buf + (bt0 + nt) * 512 + lane * 8);
#pragma unroll
    for (int mt = 0; mt < 4; mt++)
#pragma unroll
      for (int nt = 0; nt < 4; nt++)
        acc[mt][nt] = mfma_bf16(a[mt], b[nt], acc[mt][nt]);
  }
}

// ------------------- fused QKV GEMM + RMSNorm + RoPE + V^T -----------------
__global__ __launch_bounds__(256) void gemm_qkv(
    const unsigned short* __restrict__ Ap, const unsigned short* __restrict__ Bp,
    const float* __restrict__ colscale, const float2* __restrict__ ropetab,
    const float* __restrict__ nw, unsigned short* __restrict__ Qb,
    unsigned short* __restrict__ Kb, unsigned short* __restrict__ Vt) {
  __shared__ float4 smem4[2192];            // 35072 B (core 32KB / epilogue)
  char* smem = (char*)smem4;
  const int tid = threadIdx.x;
  const int lane = tid & 63, wave = tid >> 6;
  const int q = lane >> 4, l16 = lane & 15;
  // XCD-strip swizzle: XCD x owns bx in [4x,4x+4) x all by  (B-slab 2MB -> L2)
  const int wg = (int)blockIdx.y * 32 + (int)blockIdx.x;
  const int xcd = wg & 7, cix = wg >> 3;
  const int bxn = (xcd << 2) | (cix & 3), byn = cix >> 2;
  const int m0 = byn * 128, n0 = bxn * 128;
  const int wm = (wave & 1) * 64, wn = (wave >> 1) * 64;

  floatx4 acc[4][4] = {};
  gemm_core(Ap, Bp, (unsigned short*)smem, m0 >> 4, n0 >> 4, cD / 32, tid, acc);

  float sc[4];
#pragma unroll
  for (int nt = 0; nt < 4; nt++) sc[nt] = colscale[n0 + wn + nt * 16 + l16];
#pragma unroll
  for (int mt = 0; mt < 4; mt++)
#pragma unroll
    for (int nt = 0; nt < 4; nt++)
#pragma unroll
      for (int rg = 0; rg < 4; rg++) acc[mt][nt][rg] *= sc[nt];

  __syncthreads();                     // core LDS reads done before epi writes
  const int tile_n = bxn;
  const int bi = m0 >> 11, sbase = m0 & (cS - 1);

  if (tile_n >= 24) {
    // V: transpose through LDS, store Vt[.,d,s]
    unsigned short* T = (unsigned short*)smem;   // [128 d][136 s]
#pragma unroll
    for (int mt = 0; mt < 4; mt++)
#pragma unroll
      for (int nt = 0; nt < 4; nt++) {
        short4v pk;
#pragma unroll
        for (int rg = 0; rg < 4; rg++) pk[rg] = (short)f2bf(acc[mt][nt][rg]);
        *(short4v*)(T + (wn + nt * 16 + l16) * 136 + (wm + mt * 16 + q * 4)) = pk;
      }
    __syncthreads();
    const int d = tid >> 1, sh = (tid & 1) * 64;
    unsigned short* dst = Vt + ((size_t)(bi * cKVH + (tile_n - 24)) * cHD + d) * cS
                          + sbase + sh;
#pragma unroll
    for (int j = 0; j < 8; j++)
      *(ushort8v*)(dst + j * 8) = *(const ushort8v*)(T + d * 136 + sh + j * 8);
  } else {
    // Q/K: RMSNorm + RoPE
    unsigned short* W = (unsigned short*)smem;   // 4 waves x 4096 ushorts
    float* ssq  = (float*)(smem + 32768);        // [2][128]
    float* invs = (float*)(smem + 33792);        // [128]

    float sl[4][4];
#pragma unroll
    for (int mt = 0; mt < 4; mt++)
#pragma unroll
      for (int rg = 0; rg < 4; rg++) {
        float s = 0.f;
#pragma unroll
        for (int nt = 0; nt < 4; nt++) s += acc[mt][nt][rg] * acc[mt][nt][rg];
        s += __shfl_xor(s, 1); s += __shfl_xor(s, 2);
        s += __shfl_xor(s, 4); s += __shfl_xor(s, 8);
        sl[mt][rg] = s;
      }
    unsigned short* Wo = W + wave * 4096;
#pragma unroll
    for (int mt = 0; mt < 4; mt++)
#pragma unroll
      for (int nt = 0; nt < 4; nt++) {
        short4v pk;
#pragma unroll
        for (int rg = 0; rg < 4; rg++) pk[rg] = (short)f2bf(acc[mt][nt][rg]);
        *(short4v*)(Wo + (mt * 4 + nt) * 256 + lane * 4) = pk;
      }
    if (l16 == 0) {
#pragma unroll
      for (int mt = 0; mt < 4; mt++)
#pragma unroll
        for (int rg = 0; rg < 4; rg++)
          ssq[((wave >> 1) & 1) * 128 + wm + mt * 16 + q * 4 + rg] = sl[mt][rg];
    }
    __syncthreads();
    if (tid < 128)
      invs[tid] = rsqrtf((ssq[tid] + ssq[128 + tid]) * (1.0f / cHD) + cEPS);
    __syncthreads();

    const unsigned short* Wp = W + (wave ^ 2) * 4096;
    const int wn1 = wave >> 1;
    const float* nwb = nw + (tile_n < 16 ? 0 : cHD);
    float wown[4], wpar[4];
#pragma unroll
    for (int nt = 0; nt < 4; nt++) {
      wown[nt] = nwb[wn1 * 64 + nt * 16 + l16];
      wpar[nt] = nwb[(wn1 ^ 1) * 64 + nt * 16 + l16];
    }
    unsigned short* dstb = (tile_n < 16)
        ? Qb + ((size_t)(bi * cH + tile_n) * cS) * cHD
        : Kb + ((size_t)(bi * cKVH + (tile_n - 16)) * cS) * cHD;
#pragma unroll
    for (int mt = 0; mt < 4; mt++) {
      float iv[4];
#pragma unroll
      for (int rg = 0; rg < 4; rg++) iv[rg] = invs[wm + mt * 16 + q * 4 + rg];
#pragma unroll
      for (int nt = 0; nt < 4; nt++) {
        short4v pk = *(const short4v*)(Wp + (mt * 4 + nt) * 256 + lane * 4);
#pragma unroll
        for (int rg = 0; rg < 4; rg++) {
          int srow = sbase + wm + mt * 16 + q * 4 + rg;
          float2 cs = ropetab[srow * 64 + nt * 16 + l16];
          float nown = acc[mt][nt][rg] * iv[rg] * wown[nt];
          float npar = bf2f((unsigned short)pk[rg]) * iv[rg] * wpar[nt];
          float o = wn1 == 0 ? nown * cs.x - npar * cs.y
                             : nown * cs.x + npar * cs.y;
          dstb[(size_t)srow * cHD + wn1 * 64 + nt * 16 + l16] = f2bf(o);
        }
      }
    }
  }
}

// ------------------- O-proj GEMM with fused flag-output --------------------
__global__ __launch_bounds__(256) void gemm_out(
    const unsigned short* __restrict__ Ap, const unsigned short* __restrict__ Bp,
    const float* __restrict__ colscale, void* __restrict__ Cout,
    const int* __restrict__ flag, int N, int nkb) {
  __shared__ unsigned short SM[16384];      // 32 KB core staging
  const int tid = threadIdx.x;
  const int lane = tid & 63, wave = tid >> 6;
  const int q = lane >> 4, l16 = lane & 15;
  // XCD-strip swizzle: XCD x owns bx in [2x,2x+2) x all by
  const int wg = (int)blockIdx.y * 16 + (int)blockIdx.x;
  const int xcd = wg & 7, cix = wg >> 3;
  const int bxn = (xcd << 1) | (cix & 1), byn = cix >> 1;
  const int m0 = byn * 128, n0 = bxn * 128;
  const int wm = (wave & 1) * 64, wn = (wave >> 1) * 64;

  floatx4 acc[4][4] = {};
  gemm_core(Ap, Bp, SM, m0 >> 4, n0 >> 4, nkb, tid, acc);

  const int f = *flag;
#pragma unroll
  for (int mt = 0; mt < 4; mt++) {
    int r0 = m0 + wm + mt * 16 + q * 4;
#pragma unroll
    for (int nt = 0; nt < 4; nt++) {
      int cn = n0 + wn + nt * 16 + l16;
      float sc = colscale[cn];
#pragma unroll
      for (int rg = 0; rg < 4; rg++) {
        float v = acc[mt][nt][rg] * sc;
        if (f) ((unsigned short*)Cout)[(size_t)(r0 + rg) * N + cn] = f2bf(v);
        else   ((float*)Cout)[(size_t)(r0 + rg) * N + cn] = v;
      }
    }
  }
}

// --------------------------- flash attention (R9) --------------------------
// q-split waves (16 q rows/wave, 64/block).  32-kv windows, K tile [32][128]
// + V tile [128][32] both double-buffered in 32KB LDS -> 4 blocks/CU.
// K staged with sigma row-permutation (P values form K=32 MFMA A-fragments
// directly) + chunk XOR swizzle; V staged [d][kv] with kv-chunk XOR swizzle
// by (d&3).  All swizzles applied on the *global source* address (linear
// global_load_lds dest) and reproduced on the LDS read side.
// No-max softmax in exp2 domain; epilogue emits O-proj A-fragments.
__global__ __launch_bounds__(256, 4) void attn(
    const unsigned short* __restrict__ Qb, const unsigned short* __restrict__ Kb,
    const unsigned short* __restrict__ Vt, unsigned short* __restrict__ AOp) {
  __shared__ unsigned short SM[16384];       // 32 KB: (K 8KB + V 8KB) x2 bufs
  const int tid = threadIdx.x;
  const int lane = tid & 63, wv = tid >> 6;
  const int q = lane >> 4, l16 = lane & 15;
  const int bi = blockIdx.z, h = blockIdx.y;
  const int kh = h >> 1;
  const int bx = (int)blockIdx.x;
  // paired mapping: blocks (2i,2i+1) -> qt {i, 31-i}; each consecutive pair
  // is constant total work (one-round residency: 1024 blocks = 4/CU exactly).
  const int qt = (bx & 1) ? (31 - (bx >> 1)) : (bx >> 1);
  const int q0 = qt * 64;
  const int q0w = q0 + wv * 16;

  const unsigned short* Qbase = Qb + ((size_t)(bi * cH + h) * cS + q0w) * cHD;
  const unsigned short* Kbase = Kb + ((size_t)(bi * cKVH + kh) * cS) * cHD;
  const unsigned short* Vbase = Vt + ((size_t)(bi * cKVH + kh) * cHD) * cS;

  short8v qa[4];
#pragma unroll
  for (int c = 0; c < 4; c++)
    qa[c] = *(const short8v*)(Qbase + (size_t)l16 * cHD + c * 32 + q * 8);

  floatx4 oacc[8] = {};
  float lp = 0.f;

  // K staging source offsets: LDS visible row r (0..31) holds K[kv0+sig(r)],
  // stored chunk u holds source HD-chunk u^(r&15).
  int koff[2];
#pragma unroll
  for (int i = 0; i < 2; i++) {
    int s = (wv * 2 + i) * 64 + lane;
    int r = s >> 4, u = (s & 15) ^ (r & 15);
    int sig = ((r >> 2) & 3) * 8 + ((r >> 4) & 1) * 4 + (r & 3);
    koff[i] = sig * cHD + u * 8;
  }
  // V staging source offsets: LDS [128 d][32 kv]; row d stored kv-chunk c
  // holds source kv-chunk c^(d&3).
  int voff[2];
#pragma unroll
  for (int i = 0; i < 2; i++) {
    int s = (wv * 2 + i) * 64 + lane;
    int d = s >> 2, c2 = (s & 3) ^ (d & 3);
    voff[i] = d * cS + c2 * 8;
  }

  const int nwin = 2 * qt + 2;
  auto stage = [&](int win) {
    const int buf = (win & 1) * 8192;
    const int kv0 = win * 32;
    unsigned short* Kdst = SM + buf + (wv * 2) * 512;
    unsigned short* Vdst = SM + buf + 4096 + (wv * 2) * 512;
#pragma unroll
    for (int i = 0; i < 2; i++)
      gl_lds16(Kbase + (size_t)kv0 * cHD + koff[i], Kdst + i * 512);
#pragma unroll
    for (int i = 0; i < 2; i++)
      gl_lds16(Vbase + (size_t)kv0 + voff[i], Vdst + i * 512);
  };

  stage(0);
  for (int win = 0; win < nwin; win++) {
    __syncthreads();
    if (win + 1 < nwin) stage(win + 1);
    const int kv0 = win * 32;
    if (kv0 <= q0w + 15) {            // wave-uniform: window intersects rows
      const unsigned short* Ks = SM + (win & 1) * 8192;
      const unsigned short* Vs = Ks + 4096;

      floatx4 sres[2] = {};
#pragma unroll
      for (int c = 0; c < 4; c++) {
        short8v kf[2];
#pragma unroll
        for (int ntk = 0; ntk < 2; ntk++)
          kf[ntk] = *(const short8v*)(Ks + (ntk * 16 + l16) * 128 +
                                      (((c * 4 + q) ^ l16) * 8));
#pragma unroll
        for (int ntk = 0; ntk < 2; ntk++)
          sres[ntk] = mfma_bf16(kf[ntk], qa[c], sres[ntk]);
      }

      const bool maskw = (kv0 + 31 > q0w);
      short8v pa8;
#pragma unroll
      for (int ntk = 0; ntk < 2; ntk++) {
#pragma unroll
        for (int rg = 0; rg < 4; rg++) {
          float e = exp2f(sres[ntk][rg] * cSCL2);
          if (maskw) {
            // actual kv of visible slot (ntk,q,rg) under sigma; q row = l16
            int kvloc = q * 8 + ntk * 4 + rg;
            if (kv0 + kvloc > q0w + l16) e = 0.f;
          }
          lp += e;
          pa8[ntk * 4 + rg] = (short)f2bf(e);
        }
      }

#pragma unroll
      for (int db = 0; db < 8; db++) {
        short8v vb = *(const short8v*)(Vs + (db * 16 + l16) * 32 +
                                       ((q ^ (l16 & 3)) * 8));
        oacc[db] = mfma_bf16(pa8, vb, oacc[db]);
      }
    }
  }

  float lf = lp;
  lf += __shfl_xor(lf, 16);
  lf += __shfl_xor(lf, 32);
  float li[4];
#pragma unroll
  for (int rg = 0; rg < 4; rg++) li[rg] = 1.0f / __shfl(lf, q * 4 + rg);

  // ---- epilogue: O (C-layout) -> LDS transpose -> packed A-fragments ----
  __syncthreads();                     // all waves done reading staging LDS
  unsigned short* T = SM + wv * 16 * 136;   // per-wave [16 s][136 d]
#pragma unroll
  for (int rg = 0; rg < 4; rg++)
#pragma unroll
    for (int db = 0; db < 8; db++)
      T[(q * 4 + rg) * 136 + db * 16 + l16] = f2bf(oacc[db][rg] * li[rg]);
  // wave-private region; same-wave LDS ops are ordered -> no barrier
  const int mtile = (bi * cS + q0w) >> 4;
#pragma unroll
  for (int kbl = 0; kbl < 4; kbl++) {
    short8v fr = *(const short8v*)(T + l16 * 136 + kbl * 32 + q * 8);
    *(short8v*)(AOp + ((size_t)mtile * 64 + h * 4 + kbl) * 512 + lane * 8) = fr;
  }
}

// --------------------------- launch ----------------------------------------
extern "C" void kernel_launch(void* const* d_in, const int* in_sizes, int n_in,
                              void* d_out, int out_size, void* d_ws, size_t ws_size,
                              hipStream_t stream) {
  (void)in_sizes; (void)n_in; (void)out_size; (void)ws_size;
  char* ws = (char*)d_ws;
  size_t off = 0;
  auto alloc = [&](size_t bytes) -> char* {
    char* p = ws + off;
    off += (bytes + 255) & ~((size_t)255);
    return p;
  };
  int* flag            = (int*)alloc(256);
  float2* ropetab      = (float2*)alloc((size_t)cS * 64 * 8);
  float* nw            = (float*)alloc(256 * 4);
  float* scat          = (float*)alloc(4096 * 4);
  float* so            = (float*)alloc(2048 * 4);
  unsigned short* xp   = (unsigned short*)alloc((size_t)cM * cD * 2);
  unsigned short* wp   = (unsigned short*)alloc((size_t)cNqkv * cD * 2);
  unsigned short* wop  = (unsigned short*)alloc((size_t)cD * cH * cHD * 2);
  unsigned short* Qb   = (unsigned short*)alloc((size_t)cB * cH * cS * cHD * 2);
  unsigned short* Kb   = (unsigned short*)alloc((size_t)cB * cKVH * cS * cHD * 2);
  unsigned short* Vt   = (unsigned short*)alloc((size_t)cB * cKVH * cHD * cS * 2);
  unsigned short* AOp  = (unsigned short*)alloc((size_t)cM * cD * 2);

  detect_dtype<<<1, 256, 0, stream>>>((const unsigned*)d_in[0], flag);
  conv_small<<<25, 256, 0, stream>>>(d_in[9], d_in[10], d_in[2], d_in[4], d_in[6],
                                     d_in[8], nw, scat, so, flag);
  rope_pack<<<(cS * 64 + 255) / 256, 256, 0, stream>>>(d_in[11], d_in[12], ropetab, flag);
  pack_frag<<<dim3(256, 8), 256, 0, stream>>>(d_in[0], xp, 2048, 0, flag);
  pack_wqkv<<<dim3(256, 8), 256, 0, stream>>>((const int*)d_in[1], (const int*)d_in[3],
                                              (const int*)d_in[5], wp);
  pack_frag<<<dim3(128, 8), 256, 0, stream>>>(d_in[7], wop, 2048, 2, flag);

  gemm_qkv<<<dim3(cNqkv / 128, cM / 128), 256, 0, stream>>>(
      xp, wp, scat, ropetab, nw, Qb, Kb, Vt);
  attn<<<dim3(cS / 64, cH, cB), 256, 0, stream>>>(Qb, Kb, Vt, AOp);
  gemm_out<<<dim3(cD / 128, cM / 128), 256, 0, stream>>>(
      AOp, wop, so, d_out, flag, cD, (cH * cHD) / 32);
}

// Round 7
// 412.516 us; speedup vs baseline: 1.0723x; 1.0723x over previous
//
#include <hip/hip_runtime.h>

// ---------------------------------------------------------------------------
// QuantizedAttention: x[B,S,D] -> QKV proj (int8-quant wts) -> RMSNorm -> RoPE
//   -> causal GQA attention -> O proj.  B=2 S=2048 D=2048 H=16 KVH=8 HD=128.
// R9: attn: V back in LDS (R8's scattered global V reads were the regression:
// 16-segment/lane loads on the critical path).  Window 32 kv -> K+V tiles
// 8KB+8KB double-buffered = 32KB LDS -> 4 blocks/CU (16 waves/CU).  Keep
// K=32 PV via sigma-permuted K staging; V tile [128d][32kv] with kv-chunk
// XOR swizzle staged through pre-swizzled global source (linear LDS dest).
// Paired qt mapping (bx pairs sum to constant work) for one-round residency.
// (R14 = R9 resubmitted verbatim as a control run: R11-R13 all failed while
// every component they used passed in R9/R10; re-establishing ground truth.)
// ---------------------------------------------------------------------------

typedef __attribute__((ext_vector_type(4))) float floatx4;
typedef __attribute__((ext_vector_type(8))) short short8v;
typedef __attribute__((ext_vector_type(4))) short short4v;
typedef __attribute__((ext_vector_type(8))) unsigned short ushort8v;

#define DEVINL __device__ __forceinline__

constexpr int cB = 2, cS = 2048, cD = 2048, cH = 16, cKVH = 8, cHD = 128;
constexpr int cM = cB * cS;
constexpr int cNqkv = (cH + 2 * cKVH) * cHD;
constexpr float cEPS = 1e-6f;
// 1/sqrt(HD) * log2(e): softmax in base-2 domain (same softmax value).
constexpr float cSCL2 = 0.08838834764831845f * 1.4426950408889634f;

DEVINL unsigned short f2bf(float f) {
  unsigned u = __float_as_uint(f);
  unsigned r = ((u >> 16) & 1u) + 0x7FFFu;
  return (unsigned short)((u + r) >> 16);
}
DEVINL float bf2f(unsigned short h) { return __uint_as_float(((unsigned)h) << 16); }

DEVINL floatx4 mfma_bf16(short8v a, short8v b, floatx4 c) {
  return __builtin_amdgcn_mfma_f32_16x16x32_bf16(a, b, c, 0, 0, 0);
}

DEVINL void gl_lds16(const void* g, void* l) {
  __builtin_amdgcn_global_load_lds(
      (const __attribute__((address_space(1))) void*)g,
      (__attribute__((address_space(3))) void*)l, 16, 0, 0);
}

// --------------------------- dtype detection -------------------------------
__global__ void detect_dtype(const unsigned* __restrict__ x, int* __restrict__ flag) {
  __shared__ int cnt;
  if (threadIdx.x == 0) cnt = 0;
  __syncthreads();
  int c = 0;
  for (int i = threadIdx.x; i < 4096; i += 256) {
    unsigned e = (x[i] >> 7) & 0xFFu;
    c += (e >= 100u && e <= 142u) ? 1 : 0;
  }
  atomicAdd(&cnt, c);
  __syncthreads();
  if (threadIdx.x == 0) *flag = (cnt > 2457) ? 1 : 0;  // 1 = host is bf16
}

// --------------------------- merged small conversions ----------------------
__global__ void conv_small(const void* p9, const void* p10, const void* p2,
                           const void* p4, const void* p6, const void* p8,
                           float* __restrict__ nw, float* __restrict__ scat,
                           float* __restrict__ so, const int* __restrict__ flag) {
  int i = blockIdx.x * 256 + threadIdx.x;
  int f = *flag;
  auto rd = [&](const void* p, int idx) -> float {
    return f ? bf2f(((const unsigned short*)p)[idx]) : ((const float*)p)[idx];
  };
  if (i < 256) {
    nw[i] = (i < 128) ? rd(p9, i) : rd(p10, i - 128);
  } else if (i < 256 + 4096) {
    int j = i - 256;
    scat[j] = (j < 2048) ? rd(p2, j) : (j < 3072 ? rd(p4, j - 2048) : rd(p6, j - 3072));
  } else if (i < 256 + 4096 + 2048) {
    int j = i - 4352;
    so[j] = rd(p8, j);
  }
}

// Packed RoPE table: tab[s*64+t] = {cos[s,t], sin[s,t]} (halves equal).
__global__ void rope_pack(const void* __restrict__ cosc, const void* __restrict__ sinc,
                          float2* __restrict__ tab, const int* __restrict__ flag) {
  int i = blockIdx.x * 256 + threadIdx.x;
  if (i >= cS * 64) return;
  int s = i >> 6, t = i & 63;
  int f = *flag;
  float c = f ? bf2f(((const unsigned short*)cosc)[s * cHD + t])
              : ((const float*)cosc)[s * cHD + t];
  float sn = f ? bf2f(((const unsigned short*)sinc)[s * cHD + t])
               : ((const float*)sinc)[s * cHD + t];
  tab[i] = make_float2(c, sn);
}

// --------------------------- fragment packers ------------------------------
// Fragment layout: dst[(T*64 + kb)*512 + lane*8 + j] =
//   src[T*16 + (lane&15)][kb*32 + (lane>>4)*8 + j]
DEVINL void pack_body(const void* src, unsigned short* dst, int K, int md,
                      int Trow, int Tdst, int kc, int tid, float L[16][264]) {
#pragma unroll
  for (int it = 0; it < 16; it++) {
    int e = it * 256 + tid;
    int r = e >> 8, c = e & 255;
    size_t idx = (size_t)(Trow * 16 + r) * K + kc * 256 + c;
    float v;
    if (md == 1)      v = ((const float*)src)[idx];
    else if (md == 2) v = (float)((const int*)src)[idx];
    else              v = bf2f(((const unsigned short*)src)[idx]);
    L[r][c] = v;
  }
  __syncthreads();
  const int lane = tid & 63, w = tid >> 6;
  const int q = lane >> 4, l16 = lane & 15;
#pragma unroll
  for (int p = 0; p < 2; p++) {
    int kbl = w + p * 4;
    ushort8v o;
#pragma unroll
    for (int j = 0; j < 8; j++) o[j] = f2bf(L[l16][kbl * 32 + q * 8 + j]);
    *(ushort8v*)(dst + ((size_t)Tdst * 64 + kc * 8 + kbl) * 512 + lane * 8) = o;
  }
}

__global__ __launch_bounds__(256) void pack_frag(
    const void* __restrict__ src, unsigned short* __restrict__ dst,
    int K, int mode, const int* __restrict__ flag) {
  __shared__ float L[16][264];
  int md = mode;
  if (md == 0) md = (*flag) ? 3 : 1;
  pack_body(src, dst, K, md, blockIdx.x, blockIdx.x, blockIdx.y, threadIdx.x, L);
}

// All three QKV weight tensors in one dispatch (T: 0..127 wq, 128..191 wk,
// 192..255 wv); dst layout continuous in T (matches gemm_qkv's Bp).
__global__ __launch_bounds__(256) void pack_wqkv(
    const int* __restrict__ wq, const int* __restrict__ wk,
    const int* __restrict__ wv, unsigned short* __restrict__ dst) {
  __shared__ float L[16][264];
  int T = blockIdx.x;
  const int* src;
  int Trow;
  if (T < 128)      { src = wq; Trow = T; }
  else if (T < 192) { src = wk; Trow = T - 128; }
  else              { src = wv; Trow = T - 192; }
  pack_body(src, dst, 2048, 2, Trow, T, blockIdx.y, threadIdx.x, L);
}

// --------------------- 4-phase register-streaming GEMM core ----------------
// Wave computes 64x64 (4x4 of 16x16x32 MFMA). 4 k-phases in flight (32
// outstanding global loads/wave) to cover L2 latency; no LDS, no barriers.
DEVINL void gemm_core4(const unsigned short* __restrict__ Ap,
                       const unsigned short* __restrict__ Bp,
                       int tm0, int tn0, int nkb, int lane,
                       floatx4 acc[4][4]) {
  const unsigned short* ap[4];
  const unsigned short* bp[4];
#pragma unroll
  for (int i = 0; i < 4; i++) {
    ap[i] = Ap + ((size_t)(tm0 + i) * 64) * 512 + lane * 8;
    bp[i] = Bp + ((size_t)(tn0 + i) * 64) * 512 + lane * 8;
  }
  short8v a[4][4], b[4][4];
#pragma unroll
  for (int p = 0; p < 4; p++)
#pragma unroll
    for (int i = 0; i < 4; i++) {
      a[p][i] = *(const short8v*)(ap[i] + p * 512);
      b[p][i] = *(const short8v*)(bp[i] + p * 512);
    }
  for (int kb = 0; kb < nkb; kb += 4) {
    const bool more = (kb + 4) < nkb;
#pragma unroll
    for (int p = 0; p < 4; p++) {
#pragma unroll
      for (int mt = 0; mt < 4; mt++)
#pragma unroll
        for (int nt = 0; nt < 4; nt++)
          acc[mt][nt] = mfma_bf16(a[p][mt], b[p][nt], acc[mt][nt]);
      if (more) {
        const int o = (kb + 4 + p) * 512;
#pragma unroll
        for (int i = 0; i < 4; i++) {
          a[p][i] = *(const short8v*)(ap[i] + o);
          b[p][i] = *(const short8v*)(bp[i] + o);
        }
      }
    }
  }
}

// ------------------- fused QKV GEMM + RMSNorm + RoPE + V^T -----------------
__global__ __launch_bounds__(256) void gemm_qkv(
    const unsigned short* __restrict__ Ap, const unsigned short* __restrict__ Bp,
    const float* __restrict__ colscale, const float2* __restrict__ ropetab,
    const float* __restrict__ nw, unsigned short* __restrict__ Qb,
    unsigned short* __restrict__ Kb, unsigned short* __restrict__ Vt) {
  __shared__ float4 smem4[2192];            // 35072 B (epilogue only)
  char* smem = (char*)smem4;
  const int tid = threadIdx.x;
  const int lane = tid & 63, wave = tid >> 6;
  const int q = lane >> 4, l16 = lane & 15;
  const int m0 = blockIdx.y * 128, n0 = blockIdx.x * 128;
  const int wm = (wave & 1) * 64, wn = (wave >> 1) * 64;

  floatx4 acc[4][4] = {};
  gemm_core4(Ap, Bp, (m0 + wm) >> 4, (n0 + wn) >> 4, cD / 32, lane, acc);

  float sc[4];
#pragma unroll
  for (int nt = 0; nt < 4; nt++) sc[nt] = colscale[n0 + wn + nt * 16 + l16];
#pragma unroll
  for (int mt = 0; mt < 4; mt++)
#pragma unroll
    for (int nt = 0; nt < 4; nt++)
#pragma unroll
      for (int rg = 0; rg < 4; rg++) acc[mt][nt][rg] *= sc[nt];

  const int tile_n = blockIdx.x;
  const int bi = m0 >> 11, sbase = m0 & (cS - 1);

  if (tile_n >= 24) {
    // V: transpose through LDS, store Vt[.,d,s]
    unsigned short* T = (unsigned short*)smem;   // [128 d][136 s]
#pragma unroll
    for (int mt = 0; mt < 4; mt++)
#pragma unroll
      for (int nt = 0; nt < 4; nt++) {
        short4v pk;
#pragma unroll
        for (int rg = 0; rg < 4; rg++) pk[rg] = (short)f2bf(acc[mt][nt][rg]);
        *(short4v*)(T + (wn + nt * 16 + l16) * 136 + (wm + mt * 16 + q * 4)) = pk;
      }
    __syncthreads();
    const int d = tid >> 1, sh = (tid & 1) * 64;
    unsigned short* dst = Vt + ((size_t)(bi * cKVH + (tile_n - 24)) * cHD + d) * cS
                          + sbase + sh;
#pragma unroll
    for (int j = 0; j < 8; j++)
      *(ushort8v*)(dst + j * 8) = *(const ushort8v*)(T + d * 136 + sh + j * 8);
  } else {
    // Q/K: RMSNorm + RoPE
    unsigned short* W = (unsigned short*)smem;   // 4 waves x 4096 ushorts
    float* ssq  = (float*)(smem + 32768);        // [2][128]
    float* invs = (float*)(smem + 33792);        // [128]

    float sl[4][4];
#pragma unroll
    for (int mt = 0; mt < 4; mt++)
#pragma unroll
      for (int rg = 0; rg < 4; rg++) {
        float s = 0.f;
#pragma unroll
        for (int nt = 0; nt < 4; nt++) s += acc[mt][nt][rg] * acc[mt][nt][rg];
        s += __shfl_xor(s, 1); s += __shfl_xor(s, 2);
        s += __shfl_xor(s, 4); s += __shfl_xor(s, 8);
        sl[mt][rg] = s;
      }
    unsigned short* Wo = W + wave * 4096;
#pragma unroll
    for (int mt = 0; mt < 4; mt++)
#pragma unroll
      for (int nt = 0; nt < 4; nt++) {
        short4v pk;
#pragma unroll
        for (int rg = 0; rg < 4; rg++) pk[rg] = (short)f2bf(acc[mt][nt][rg]);
        *(short4v*)(Wo + (mt * 4 + nt) * 256 + lane * 4) = pk;
      }
    if (l16 == 0) {
#pragma unroll
      for (int mt = 0; mt < 4; mt++)
#pragma unroll
        for (int rg = 0; rg < 4; rg++)
          ssq[((wave >> 1) & 1) * 128 + wm + mt * 16 + q * 4 + rg] = sl[mt][rg];
    }
    __syncthreads();
    if (tid < 128)
      invs[tid] = rsqrtf((ssq[tid] + ssq[128 + tid]) * (1.0f / cHD) + cEPS);
    __syncthreads();

    const unsigned short* Wp = W + (wave ^ 2) * 4096;
    const int wn1 = wave >> 1;
    const float* nwb = nw + (tile_n < 16 ? 0 : cHD);
    float wown[4], wpar[4];
#pragma unroll
    for (int nt = 0; nt < 4; nt++) {
      wown[nt] = nwb[wn1 * 64 + nt * 16 + l16];
      wpar[nt] = nwb[(wn1 ^ 1) * 64 + nt * 16 + l16];
    }
    unsigned short* dstb = (tile_n < 16)
        ? Qb + ((size_t)(bi * cH + tile_n) * cS) * cHD
        : Kb + ((size_t)(bi * cKVH + (tile_n - 16)) * cS) * cHD;
#pragma unroll
    for (int mt = 0; mt < 4; mt++) {
      float iv[4];
#pragma unroll
      for (int rg = 0; rg < 4; rg++) iv[rg] = invs[wm + mt * 16 + q * 4 + rg];
#pragma unroll
      for (int nt = 0; nt < 4; nt++) {
        short4v pk = *(const short4v*)(Wp + (mt * 4 + nt) * 256 + lane * 4);
#pragma unroll
        for (int rg = 0; rg < 4; rg++) {
          int srow = sbase + wm + mt * 16 + q * 4 + rg;
          float2 cs = ropetab[srow * 64 + nt * 16 + l16];
          float nown = acc[mt][nt][rg] * iv[rg] * wown[nt];
          float npar = bf2f((unsigned short)pk[rg]) * iv[rg] * wpar[nt];
          float o = wn1 == 0 ? nown * cs.x - npar * cs.y
                             : nown * cs.x + npar * cs.y;
          dstb[(size_t)srow * cHD + wn1 * 64 + nt * 16 + l16] = f2bf(o);
        }
      }
    }
  }
}

// ------------------- O-proj GEMM with fused flag-output --------------------
__global__ __launch_bounds__(256) void gemm_out(
    const unsigned short* __restrict__ Ap, const unsigned short* __restrict__ Bp,
    const float* __restrict__ colscale, void* __restrict__ Cout,
    const int* __restrict__ flag, int N, int nkb) {
  const int tid = threadIdx.x;
  const int lane = tid & 63, wave = tid >> 6;
  const int q = lane >> 4, l16 = lane & 15;
  const int m0 = blockIdx.y * 128, n0 = blockIdx.x * 128;
  const int wm = (wave & 1) * 64, wn = (wave >> 1) * 64;

  floatx4 acc[4][4] = {};
  gemm_core4(Ap, Bp, (m0 + wm) >> 4, (n0 + wn) >> 4, nkb, lane, acc);

  const int f = *flag;
#pragma unroll
  for (int mt = 0; mt < 4; mt++) {
    int r0 = m0 + wm + mt * 16 + q * 4;
#pragma unroll
    for (int nt = 0; nt < 4; nt++) {
      int cn = n0 + wn + nt * 16 + l16;
      float sc = colscale[cn];
#pragma unroll
      for (int rg = 0; rg < 4; rg++) {
        float v = acc[mt][nt][rg] * sc;
        if (f) ((unsigned short*)Cout)[(size_t)(r0 + rg) * N + cn] = f2bf(v);
        else   ((float*)Cout)[(size_t)(r0 + rg) * N + cn] = v;
      }
    }
  }
}

// --------------------------- flash attention (R9) --------------------------
// q-split waves (16 q rows/wave, 64/block).  32-kv windows, K tile [32][128]
// + V tile [128][32] both double-buffered in 32KB LDS -> 4 blocks/CU.
// K staged with sigma row-permutation (P values form K=32 MFMA A-fragments
// directly) + chunk XOR swizzle; V staged [d][kv] with kv-chunk XOR swizzle
// by (d&3).  All swizzles applied on the *global source* address (linear
// global_load_lds dest) and reproduced on the LDS read side.
// No-max softmax in exp2 domain; epilogue emits O-proj A-fragments.
__global__ __launch_bounds__(256, 4) void attn(
    const unsigned short* __restrict__ Qb, const unsigned short* __restrict__ Kb,
    const unsigned short* __restrict__ Vt, unsigned short* __restrict__ AOp) {
  __shared__ unsigned short SM[16384];       // 32 KB: (K 8KB + V 8KB) x2 bufs
  const int tid = threadIdx.x;
  const int lane = tid & 63, wv = tid >> 6;
  const int q = lane >> 4, l16 = lane & 15;
  const int bi = blockIdx.z, h = blockIdx.y;
  const int kh = h >> 1;
  const int bx = (int)blockIdx.x;
  // paired mapping: blocks (2i,2i+1) -> qt {i, 31-i}; each consecutive pair
  // is constant total work (one-round residency: 1024 blocks = 4/CU exactly).
  const int qt = (bx & 1) ? (31 - (bx >> 1)) : (bx >> 1);
  const int q0 = qt * 64;
  const int q0w = q0 + wv * 16;

  const unsigned short* Qbase = Qb + ((size_t)(bi * cH + h) * cS + q0w) * cHD;
  const unsigned short* Kbase = Kb + ((size_t)(bi * cKVH + kh) * cS) * cHD;
  const unsigned short* Vbase = Vt + ((size_t)(bi * cKVH + kh) * cHD) * cS;

  short8v qa[4];
#pragma unroll
  for (int c = 0; c < 4; c++)
    qa[c] = *(const short8v*)(Qbase + (size_t)l16 * cHD + c * 32 + q * 8);

  floatx4 oacc[8] = {};
  float lp = 0.f;

  // K staging source offsets: LDS visible row r (0..31) holds K[kv0+sig(r)],
  // stored chunk u holds source HD-chunk u^(r&15).
  int koff[2];
#pragma unroll
  for (int i = 0; i < 2; i++) {
    int s = (wv * 2 + i) * 64 + lane;
    int r = s >> 4, u = (s & 15) ^ (r & 15);
    int sig = ((r >> 2) & 3) * 8 + ((r >> 4) & 1) * 4 + (r & 3);
    koff[i] = sig * cHD + u * 8;
  }
  // V staging source offsets: LDS [128 d][32 kv]; row d stored kv-chunk c
  // holds source kv-chunk c^(d&3).
  int voff[2];
#pragma unroll
  for (int i = 0; i < 2; i++) {
    int s = (wv * 2 + i) * 64 + lane;
    int d = s >> 2, c2 = (s & 3) ^ (d & 3);
    voff[i] = d * cS + c2 * 8;
  }

  const int nwin = 2 * qt + 2;
  auto stage = [&](int win) {
    const int buf = (win & 1) * 8192;
    const int kv0 = win * 32;
    unsigned short* Kdst = SM + buf + (wv * 2) * 512;
    unsigned short* Vdst = SM + buf + 4096 + (wv * 2) * 512;
#pragma unroll
    for (int i = 0; i < 2; i++)
      gl_lds16(Kbase + (size_t)kv0 * cHD + koff[i], Kdst + i * 512);
#pragma unroll
    for (int i = 0; i < 2; i++)
      gl_lds16(Vbase + (size_t)kv0 + voff[i], Vdst + i * 512);
  };

  stage(0);
  for (int win = 0; win < nwin; win++) {
    __syncthreads();
    if (win + 1 < nwin) stage(win + 1);
    const int kv0 = win * 32;
    if (kv0 <= q0w + 15) {            // wave-uniform: window intersects rows
      const unsigned short* Ks = SM + (win & 1) * 8192;
      const unsigned short* Vs = Ks + 4096;

      floatx4 sres[2] = {};
#pragma unroll
      for (int c = 0; c < 4; c++) {
        short8v kf[2];
#pragma unroll
        for (int ntk = 0; ntk < 2; ntk++)
          kf[ntk] = *(const short8v*)(Ks + (ntk * 16 + l16) * 128 +
                                      (((c * 4 + q) ^ l16) * 8));
#pragma unroll
        for (int ntk = 0; ntk < 2; ntk++)
          sres[ntk] = mfma_bf16(kf[ntk], qa[c], sres[ntk]);
      }

      const bool maskw = (kv0 + 31 > q0w);
      short8v pa8;
#pragma unroll
      for (int ntk = 0; ntk < 2; ntk++) {
#pragma unroll
        for (int rg = 0; rg < 4; rg++) {
          float e = exp2f(sres[ntk][rg] * cSCL2);
          if (maskw) {
            // actual kv of visible slot (ntk,q,rg) under sigma; q row = l16
            int kvloc = q * 8 + ntk * 4 + rg;
            if (kv0 + kvloc > q0w + l16) e = 0.f;
          }
          lp += e;
          pa8[ntk * 4 + rg] = (short)f2bf(e);
        }
      }

#pragma unroll
      for (int db = 0; db < 8; db++) {
        short8v vb = *(const short8v*)(Vs + (db * 16 + l16) * 32 +
                                       ((q ^ (l16 & 3)) * 8));
        oacc[db] = mfma_bf16(pa8, vb, oacc[db]);
      }
    }
  }

  float lf = lp;
  lf += __shfl_xor(lf, 16);
  lf += __shfl_xor(lf, 32);
  float li[4];
#pragma unroll
  for (int rg = 0; rg < 4; rg++) li[rg] = 1.0f / __shfl(lf, q * 4 + rg);

  // ---- epilogue: O (C-layout) -> LDS transpose -> packed A-fragments ----
  __syncthreads();                     // all waves done reading staging LDS
  unsigned short* T = SM + wv * 16 * 136;   // per-wave [16 s][136 d]
#pragma unroll
  for (int rg = 0; rg < 4; rg++)
#pragma unroll
    for (int db = 0; db < 8; db++)
      T[(q * 4 + rg) * 136 + db * 16 + l16] = f2bf(oacc[db][rg] * li[rg]);
  // wave-private region; same-wave LDS ops are ordered -> no barrier
  const int mtile = (bi * cS + q0w) >> 4;
#pragma unroll
  for (int kbl = 0; kbl < 4; kbl++) {
    short8v fr = *(const short8v*)(T + l16 * 136 + kbl * 32 + q * 8);
    *(short8v*)(AOp + ((size_t)mtile * 64 + h * 4 + kbl) * 512 + lane * 8) = fr;
  }
}

// --------------------------- launch ----------------------------------------
extern "C" void kernel_launch(void* const* d_in, const int* in_sizes, int n_in,
                              void* d_out, int out_size, void* d_ws, size_t ws_size,
                              hipStream_t stream) {
  (void)in_sizes; (void)n_in; (void)out_size; (void)ws_size;
  char* ws = (char*)d_ws;
  size_t off = 0;
  auto alloc = [&](size_t bytes) -> char* {
    char* p = ws + off;
    off += (bytes + 255) & ~((size_t)255);
    return p;
  };
  int* flag            = (int*)alloc(256);
  float2* ropetab      = (float2*)alloc((size_t)cS * 64 * 8);
  float* nw            = (float*)alloc(256 * 4);
  float* scat          = (float*)alloc(4096 * 4);
  float* so            = (float*)alloc(2048 * 4);
  unsigned short* xp   = (unsigned short*)alloc((size_t)cM * cD * 2);
  unsigned short* wp   = (unsigned short*)alloc((size_t)cNqkv * cD * 2);
  unsigned short* wop  = (unsigned short*)alloc((size_t)cD * cH * cHD * 2);
  unsigned short* Qb   = (unsigned short*)alloc((size_t)cB * cH * cS * cHD * 2);
  unsigned short* Kb   = (unsigned short*)alloc((size_t)cB * cKVH * cS * cHD * 2);
  unsigned short* Vt   = (unsigned short*)alloc((size_t)cB * cKVH * cHD * cS * 2);
  unsigned short* AOp  = (unsigned short*)alloc((size_t)cM * cD * 2);

  detect_dtype<<<1, 256, 0, stream>>>((const unsigned*)d_in[0], flag);
  conv_small<<<25, 256, 0, stream>>>(d_in[9], d_in[10], d_in[2], d_in[4], d_in[6],
                                     d_in[8], nw, scat, so, flag);
  rope_pack<<<(cS * 64 + 255) / 256, 256, 0, stream>>>(d_in[11], d_in[12], ropetab, flag);
  pack_frag<<<dim3(256, 8), 256, 0, stream>>>(d_in[0], xp, 2048, 0, flag);
  pack_wqkv<<<dim3(256, 8), 256, 0, stream>>>((const int*)d_in[1], (const int*)d_in[3],
                                              (const int*)d_in[5], wp);
  pack_frag<<<dim3(128, 8), 256, 0, stream>>>(d_in[7], wop, 2048, 2, flag);

  gemm_qkv<<<dim3(cNqkv / 128, cM / 128), 256, 0, stream>>>(
      xp, wp, scat, ropetab, nw, Qb, Kb, Vt);
  attn<<<dim3(cS / 64, cH, cB), 256, 0, stream>>>(Qb, Kb, Vt, AOp);
  gemm_out<<<dim3(cD / 128, cM / 128), 256, 0, stream>>>(
      AOp, wop, so, d_out, flag, cD, (cH * cHD) / 32);
}

// Round 9
// 396.102 us; speedup vs baseline: 1.1168x; 1.0414x over previous
//
#include <hip/hip_runtime.h>

// ---------------------------------------------------------------------------
// QuantizedAttention: x[B,S,D] -> QKV proj (int8-quant wts) -> RMSNorm -> RoPE
//   -> causal GQA attention -> O proj.  B=2 S=2048 D=2048 H=16 KVH=8 HD=128.
// R16: dispatch-merge ONLY.  detect_dtype dispatch + flag buffer KEPT exactly
// as the proven R9 (R15's per-block flag recompute is the suspect and is
// gone).  conv_small+rope_pack concatenated into prep; the three packers
// concatenated into pack_all - all bodies byte-identical to R9's, same flag
// reads, same workspace layout.  gemm_qkv / attn / gemm_out verbatim R9.
// Dispatches 9 -> 6.
// ---------------------------------------------------------------------------

typedef __attribute__((ext_vector_type(4))) float floatx4;
typedef __attribute__((ext_vector_type(8))) short short8v;
typedef __attribute__((ext_vector_type(4))) short short4v;
typedef __attribute__((ext_vector_type(8))) unsigned short ushort8v;

#define DEVINL __device__ __forceinline__

constexpr int cB = 2, cS = 2048, cD = 2048, cH = 16, cKVH = 8, cHD = 128;
constexpr int cM = cB * cS;
constexpr int cNqkv = (cH + 2 * cKVH) * cHD;
constexpr float cEPS = 1e-6f;
// 1/sqrt(HD) * log2(e): softmax in base-2 domain (same softmax value).
constexpr float cSCL2 = 0.08838834764831845f * 1.4426950408889634f;

DEVINL unsigned short f2bf(float f) {
  unsigned u = __float_as_uint(f);
  unsigned r = ((u >> 16) & 1u) + 0x7FFFu;
  return (unsigned short)((u + r) >> 16);
}
DEVINL float bf2f(unsigned short h) { return __uint_as_float(((unsigned)h) << 16); }

DEVINL floatx4 mfma_bf16(short8v a, short8v b, floatx4 c) {
  return __builtin_amdgcn_mfma_f32_16x16x32_bf16(a, b, c, 0, 0, 0);
}

DEVINL void gl_lds16(const void* g, void* l) {
  __builtin_amdgcn_global_load_lds(
      (const __attribute__((address_space(1))) void*)g,
      (__attribute__((address_space(3))) void*)l, 16, 0, 0);
}

// --------------------------- dtype detection -------------------------------
__global__ void detect_dtype(const unsigned* __restrict__ x, int* __restrict__ flag) {
  __shared__ int cnt;
  if (threadIdx.x == 0) cnt = 0;
  __syncthreads();
  int c = 0;
  for (int i = threadIdx.x; i < 4096; i += 256) {
    unsigned e = (x[i] >> 7) & 0xFFu;
    c += (e >= 100u && e <= 142u) ? 1 : 0;
  }
  atomicAdd(&cnt, c);
  __syncthreads();
  if (threadIdx.x == 0) *flag = (cnt > 2457) ? 1 : 0;  // 1 = host is bf16
}

// -------------- merged small conversions + RoPE table (prep) ---------------
// blocks 0..24: conv_small body; blocks 25..536: rope_pack body.
__global__ void prep(const void* p9, const void* p10, const void* p2,
                     const void* p4, const void* p6, const void* p8,
                     const void* __restrict__ cosc, const void* __restrict__ sinc,
                     float* __restrict__ nw, float* __restrict__ scat,
                     float* __restrict__ so, float2* __restrict__ tab,
                     const int* __restrict__ flag) {
  const int b = (int)blockIdx.x;
  int f = *flag;
  auto rd = [&](const void* p, int idx) -> float {
    return f ? bf2f(((const unsigned short*)p)[idx]) : ((const float*)p)[idx];
  };
  if (b < 25) {
    int i = b * 256 + threadIdx.x;
    if (i < 256) {
      nw[i] = (i < 128) ? rd(p9, i) : rd(p10, i - 128);
    } else if (i < 256 + 4096) {
      int j = i - 256;
      scat[j] = (j < 2048) ? rd(p2, j) : (j < 3072 ? rd(p4, j - 2048) : rd(p6, j - 3072));
    } else if (i < 256 + 4096 + 2048) {
      int j = i - 4352;
      so[j] = rd(p8, j);
    }
  } else {
    int i = (b - 25) * 256 + threadIdx.x;
    if (i >= cS * 64) return;
    int s = i >> 6, t = i & 63;
    float c = f ? bf2f(((const unsigned short*)cosc)[s * cHD + t])
                : ((const float*)cosc)[s * cHD + t];
    float sn = f ? bf2f(((const unsigned short*)sinc)[s * cHD + t])
                 : ((const float*)sinc)[s * cHD + t];
    tab[i] = make_float2(c, sn);
  }
}

// --------------------------- fragment packers ------------------------------
// Fragment layout: dst[(T*64 + kb)*512 + lane*8 + j] =
//   src[T*16 + (lane&15)][kb*32 + (lane>>4)*8 + j]
DEVINL void pack_body(const void* src, unsigned short* dst, int K, int md,
                      int Trow, int Tdst, int kc, int tid, float L[16][264]) {
#pragma unroll
  for (int it = 0; it < 16; it++) {
    int e = it * 256 + tid;
    int r = e >> 8, c = e & 255;
    size_t idx = (size_t)(Trow * 16 + r) * K + kc * 256 + c;
    float v;
    if (md == 1)      v = ((const float*)src)[idx];
    else if (md == 2) v = (float)((const int*)src)[idx];
    else              v = bf2f(((const unsigned short*)src)[idx]);
    L[r][c] = v;
  }
  __syncthreads();
  const int lane = tid & 63, w = tid >> 6;
  const int q = lane >> 4, l16 = lane & 15;
#pragma unroll
  for (int p = 0; p < 2; p++) {
    int kbl = w + p * 4;
    ushort8v o;
#pragma unroll
    for (int j = 0; j < 8; j++) o[j] = f2bf(L[l16][kbl * 32 + q * 8 + j]);
    *(ushort8v*)(dst + ((size_t)Tdst * 64 + kc * 8 + kbl) * 512 + lane * 8) = o;
  }
}

// All packers in one dispatch.  bx<256: x -> xp (flag-selected dtype);
// bx in [256,512): wq/wk/wv -> wp (int); bx in [512,640): wo -> wop (int).
__global__ __launch_bounds__(256) void pack_all(
    const void* __restrict__ x, const int* __restrict__ wq,
    const int* __restrict__ wk, const int* __restrict__ wv,
    const int* __restrict__ wo, unsigned short* __restrict__ xp,
    unsigned short* __restrict__ wp, unsigned short* __restrict__ wop,
    const int* __restrict__ flag) {
  __shared__ float L[16][264];
  const int bx = (int)blockIdx.x, kc = (int)blockIdx.y, tid = threadIdx.x;
  if (bx < 256) {
    int md = (*flag) ? 3 : 1;
    pack_body(x, xp, 2048, md, bx, bx, kc, tid, L);
  } else if (bx < 512) {
    int T = bx - 256;
    const int* src;
    int Trow;
    if (T < 128)      { src = wq; Trow = T; }
    else if (T < 192) { src = wk; Trow = T - 128; }
    else              { src = wv; Trow = T - 192; }
    pack_body(src, wp, 2048, 2, Trow, T, kc, tid, L);
  } else {
    int T = bx - 512;
    pack_body(wo, wop, 2048, 2, T, T, kc, tid, L);
  }
}

// --------------------- 4-phase register-streaming GEMM core ----------------
// Wave computes 64x64 (4x4 of 16x16x32 MFMA). 4 k-phases in flight (32
// outstanding global loads/wave) to cover L2 latency; no LDS, no barriers.
DEVINL void gemm_core4(const unsigned short* __restrict__ Ap,
                       const unsigned short* __restrict__ Bp,
                       int tm0, int tn0, int nkb, int lane,
                       floatx4 acc[4][4]) {
  const unsigned short* ap[4];
  const unsigned short* bp[4];
#pragma unroll
  for (int i = 0; i < 4; i++) {
    ap[i] = Ap + ((size_t)(tm0 + i) * 64) * 512 + lane * 8;
    bp[i] = Bp + ((size_t)(tn0 + i) * 64) * 512 + lane * 8;
  }
  short8v a[4][4], b[4][4];
#pragma unroll
  for (int p = 0; p < 4; p++)
#pragma unroll
    for (int i = 0; i < 4; i++) {
      a[p][i] = *(const short8v*)(ap[i] + p * 512);
      b[p][i] = *(const short8v*)(bp[i] + p * 512);
    }
  for (int kb = 0; kb < nkb; kb += 4) {
    const bool more = (kb + 4) < nkb;
#pragma unroll
    for (int p = 0; p < 4; p++) {
#pragma unroll
      for (int mt = 0; mt < 4; mt++)
#pragma unroll
        for (int nt = 0; nt < 4; nt++)
          acc[mt][nt] = mfma_bf16(a[p][mt], b[p][nt], acc[mt][nt]);
      if (more) {
        const int o = (kb + 4 + p) * 512;
#pragma unroll
        for (int i = 0; i < 4; i++) {
          a[p][i] = *(const short8v*)(ap[i] + o);
          b[p][i] = *(const short8v*)(bp[i] + o);
        }
      }
    }
  }
}

// ------------------- fused QKV GEMM + RMSNorm + RoPE + V^T -----------------
__global__ __launch_bounds__(256) void gemm_qkv(
    const unsigned short* __restrict__ Ap, const unsigned short* __restrict__ Bp,
    const float* __restrict__ colscale, const float2* __restrict__ ropetab,
    const float* __restrict__ nw, unsigned short* __restrict__ Qb,
    unsigned short* __restrict__ Kb, unsigned short* __restrict__ Vt) {
  __shared__ float4 smem4[2192];            // 35072 B (epilogue only)
  char* smem = (char*)smem4;
  const int tid = threadIdx.x;
  const int lane = tid & 63, wave = tid >> 6;
  const int q = lane >> 4, l16 = lane & 15;
  const int m0 = blockIdx.y * 128, n0 = blockIdx.x * 128;
  const int wm = (wave & 1) * 64, wn = (wave >> 1) * 64;

  floatx4 acc[4][4] = {};
  gemm_core4(Ap, Bp, (m0 + wm) >> 4, (n0 + wn) >> 4, cD / 32, lane, acc);

  float sc[4];
#pragma unroll
  for (int nt = 0; nt < 4; nt++) sc[nt] = colscale[n0 + wn + nt * 16 + l16];
#pragma unroll
  for (int mt = 0; mt < 4; mt++)
#pragma unroll
    for (int nt = 0; nt < 4; nt++)
#pragma unroll
      for (int rg = 0; rg < 4; rg++) acc[mt][nt][rg] *= sc[nt];

  const int tile_n = blockIdx.x;
  const int bi = m0 >> 11, sbase = m0 & (cS - 1);

  if (tile_n >= 24) {
    // V: transpose through LDS, store Vt[.,d,s]
    unsigned short* T = (unsigned short*)smem;   // [128 d][136 s]
#pragma unroll
    for (int mt = 0; mt < 4; mt++)
#pragma unroll
      for (int nt = 0; nt < 4; nt++) {
        short4v pk;
#pragma unroll
        for (int rg = 0; rg < 4; rg++) pk[rg] = (short)f2bf(acc[mt][nt][rg]);
        *(short4v*)(T + (wn + nt * 16 + l16) * 136 + (wm + mt * 16 + q * 4)) = pk;
      }
    __syncthreads();
    const int d = tid >> 1, sh = (tid & 1) * 64;
    unsigned short* dst = Vt + ((size_t)(bi * cKVH + (tile_n - 24)) * cHD + d) * cS
                          + sbase + sh;
#pragma unroll
    for (int j = 0; j < 8; j++)
      *(ushort8v*)(dst + j * 8) = *(const ushort8v*)(T + d * 136 + sh + j * 8);
  } else {
    // Q/K: RMSNorm + RoPE
    unsigned short* W = (unsigned short*)smem;   // 4 waves x 4096 ushorts
    float* ssq  = (float*)(smem + 32768);        // [2][128]
    float* invs = (float*)(smem + 33792);        // [128]

    float sl[4][4];
#pragma unroll
    for (int mt = 0; mt < 4; mt++)
#pragma unroll
      for (int rg = 0; rg < 4; rg++) {
        float s = 0.f;
#pragma unroll
        for (int nt = 0; nt < 4; nt++) s += acc[mt][nt][rg] * acc[mt][nt][rg];
        s += __shfl_xor(s, 1); s += __shfl_xor(s, 2);
        s += __shfl_xor(s, 4); s += __shfl_xor(s, 8);
        sl[mt][rg] = s;
      }
    unsigned short* Wo = W + wave * 4096;
#pragma unroll
    for (int mt = 0; mt < 4; mt++)
#pragma unroll
      for (int nt = 0; nt < 4; nt++) {
        short4v pk;
#pragma unroll
        for (int rg = 0; rg < 4; rg++) pk[rg] = (short)f2bf(acc[mt][nt][rg]);
        *(short4v*)(Wo + (mt * 4 + nt) * 256 + lane * 4) = pk;
      }
    if (l16 == 0) {
#pragma unroll
      for (int mt = 0; mt < 4; mt++)
#pragma unroll
        for (int rg = 0; rg < 4; rg++)
          ssq[((wave >> 1) & 1) * 128 + wm + mt * 16 + q * 4 + rg] = sl[mt][rg];
    }
    __syncthreads();
    if (tid < 128)
      invs[tid] = rsqrtf((ssq[tid] + ssq[128 + tid]) * (1.0f / cHD) + cEPS);
    __syncthreads();

    const unsigned short* Wp = W + (wave ^ 2) * 4096;
    const int wn1 = wave >> 1;
    const float* nwb = nw + (tile_n < 16 ? 0 : cHD);
    float wown[4], wpar[4];
#pragma unroll
    for (int nt = 0; nt < 4; nt++) {
      wown[nt] = nwb[wn1 * 64 + nt * 16 + l16];
      wpar[nt] = nwb[(wn1 ^ 1) * 64 + nt * 16 + l16];
    }
    unsigned short* dstb = (tile_n < 16)
        ? Qb + ((size_t)(bi * cH + tile_n) * cS) * cHD
        : Kb + ((size_t)(bi * cKVH + (tile_n - 16)) * cS) * cHD;
#pragma unroll
    for (int mt = 0; mt < 4; mt++) {
      float iv[4];
#pragma unroll
      for (int rg = 0; rg < 4; rg++) iv[rg] = invs[wm + mt * 16 + q * 4 + rg];
#pragma unroll
      for (int nt = 0; nt < 4; nt++) {
        short4v pk = *(const short4v*)(Wp + (mt * 4 + nt) * 256 + lane * 4);
#pragma unroll
        for (int rg = 0; rg < 4; rg++) {
          int srow = sbase + wm + mt * 16 + q * 4 + rg;
          float2 cs = ropetab[srow * 64 + nt * 16 + l16];
          float nown = acc[mt][nt][rg] * iv[rg] * wown[nt];
          float npar = bf2f((unsigned short)pk[rg]) * iv[rg] * wpar[nt];
          float o = wn1 == 0 ? nown * cs.x - npar * cs.y
                             : nown * cs.x + npar * cs.y;
          dstb[(size_t)srow * cHD + wn1 * 64 + nt * 16 + l16] = f2bf(o);
        }
      }
    }
  }
}

// ------------------- O-proj GEMM with fused flag-output --------------------
__global__ __launch_bounds__(256) void gemm_out(
    const unsigned short* __restrict__ Ap, const unsigned short* __restrict__ Bp,
    const float* __restrict__ colscale, void* __restrict__ Cout,
    const int* __restrict__ flag, int N, int nkb) {
  const int tid = threadIdx.x;
  const int lane = tid & 63, wave = tid >> 6;
  const int q = lane >> 4, l16 = lane & 15;
  const int m0 = blockIdx.y * 128, n0 = blockIdx.x * 128;
  const int wm = (wave & 1) * 64, wn = (wave >> 1) * 64;

  floatx4 acc[4][4] = {};
  gemm_core4(Ap, Bp, (m0 + wm) >> 4, (n0 + wn) >> 4, nkb, lane, acc);

  const int f = *flag;
#pragma unroll
  for (int mt = 0; mt < 4; mt++) {
    int r0 = m0 + wm + mt * 16 + q * 4;
#pragma unroll
    for (int nt = 0; nt < 4; nt++) {
      int cn = n0 + wn + nt * 16 + l16;
      float sc = colscale[cn];
#pragma unroll
      for (int rg = 0; rg < 4; rg++) {
        float v = acc[mt][nt][rg] * sc;
        if (f) ((unsigned short*)Cout)[(size_t)(r0 + rg) * N + cn] = f2bf(v);
        else   ((float*)Cout)[(size_t)(r0 + rg) * N + cn] = v;
      }
    }
  }
}

// --------------------------- flash attention (R9, unchanged) ---------------
// q-split waves (16 q rows/wave, 64/block).  32-kv windows, K tile [32][128]
// + V tile [128][32] both double-buffered in 32KB LDS -> 4 blocks/CU.
// K staged with sigma row-permutation (P values form K=32 MFMA A-fragments
// directly) + chunk XOR swizzle; V staged [d][kv] with kv-chunk XOR swizzle
// by (d&3).  All swizzles applied on the *global source* address (linear
// global_load_lds dest) and reproduced on the LDS read side.
// No-max softmax in exp2 domain; epilogue emits O-proj A-fragments.
__global__ __launch_bounds__(256, 4) void attn(
    const unsigned short* __restrict__ Qb, const unsigned short* __restrict__ Kb,
    const unsigned short* __restrict__ Vt, unsigned short* __restrict__ AOp) {
  __shared__ unsigned short SM[16384];       // 32 KB: (K 8KB + V 8KB) x2 bufs
  const int tid = threadIdx.x;
  const int lane = tid & 63, wv = tid >> 6;
  const int q = lane >> 4, l16 = lane & 15;
  const int bi = blockIdx.z, h = blockIdx.y;
  const int kh = h >> 1;
  const int bx = (int)blockIdx.x;
  // paired mapping: blocks (2i,2i+1) -> qt {i, 31-i}; each consecutive pair
  // is constant total work (one-round residency: 1024 blocks = 4/CU exactly).
  const int qt = (bx & 1) ? (31 - (bx >> 1)) : (bx >> 1);
  const int q0 = qt * 64;
  const int q0w = q0 + wv * 16;

  const unsigned short* Qbase = Qb + ((size_t)(bi * cH + h) * cS + q0w) * cHD;
  const unsigned short* Kbase = Kb + ((size_t)(bi * cKVH + kh) * cS) * cHD;
  const unsigned short* Vbase = Vt + ((size_t)(bi * cKVH + kh) * cHD) * cS;

  short8v qa[4];
#pragma unroll
  for (int c = 0; c < 4; c++)
    qa[c] = *(const short8v*)(Qbase + (size_t)l16 * cHD + c * 32 + q * 8);

  floatx4 oacc[8] = {};
  float lp = 0.f;

  // K staging source offsets: LDS visible row r (0..31) holds K[kv0+sig(r)],
  // stored chunk u holds source HD-chunk u^(r&15).
  int koff[2];
#pragma unroll
  for (int i = 0; i < 2; i++) {
    int s = (wv * 2 + i) * 64 + lane;
    int r = s >> 4, u = (s & 15) ^ (r & 15);
    int sig = ((r >> 2) & 3) * 8 + ((r >> 4) & 1) * 4 + (r & 3);
    koff[i] = sig * cHD + u * 8;
  }
  // V staging source offsets: LDS [128 d][32 kv]; row d stored kv-chunk c
  // holds source kv-chunk c^(d&3).
  int voff[2];
#pragma unroll
  for (int i = 0; i < 2; i++) {
    int s = (wv * 2 + i) * 64 + lane;
    int d = s >> 2, c2 = (s & 3) ^ (d & 3);
    voff[i] = d * cS + c2 * 8;
  }

  const int nwin = 2 * qt + 2;
  auto stage = [&](int win) {
    const int buf = (win & 1) * 8192;
    const int kv0 = win * 32;
    unsigned short* Kdst = SM + buf + (wv * 2) * 512;
    unsigned short* Vdst = SM + buf + 4096 + (wv * 2) * 512;
#pragma unroll
    for (int i = 0; i < 2; i++)
      gl_lds16(Kbase + (size_t)kv0 * cHD + koff[i], Kdst + i * 512);
#pragma unroll
    for (int i = 0; i < 2; i++)
      gl_lds16(Vbase + (size_t)kv0 + voff[i], Vdst + i * 512);
  };

  stage(0);
  for (int win = 0; win < nwin; win++) {
    __syncthreads();
    if (win + 1 < nwin) stage(win + 1);
    const int kv0 = win * 32;
    if (kv0 <= q0w + 15) {            // wave-uniform: window intersects rows
      const unsigned short* Ks = SM + (win & 1) * 8192;
      const unsigned short* Vs = Ks + 4096;

      floatx4 sres[2] = {};
#pragma unroll
      for (int c = 0; c < 4; c++) {
        short8v kf[2];
#pragma unroll
        for (int ntk = 0; ntk < 2; ntk++)
          kf[ntk] = *(const short8v*)(Ks + (ntk * 16 + l16) * 128 +
                                      (((c * 4 + q) ^ l16) * 8));
#pragma unroll
        for (int ntk = 0; ntk < 2; ntk++)
          sres[ntk] = mfma_bf16(kf[ntk], qa[c], sres[ntk]);
      }

      const bool maskw = (kv0 + 31 > q0w);
      short8v pa8;
#pragma unroll
      for (int ntk = 0; ntk < 2; ntk++) {
#pragma unroll
        for (int rg = 0; rg < 4; rg++) {
          float e = exp2f(sres[ntk][rg] * cSCL2);
          if (maskw) {
            // actual kv of visible slot (ntk,q,rg) under sigma; q row = l16
            int kvloc = q * 8 + ntk * 4 + rg;
            if (kv0 + kvloc > q0w + l16) e = 0.f;
          }
          lp += e;
          pa8[ntk * 4 + rg] = (short)f2bf(e);
        }
      }

#pragma unroll
      for (int db = 0; db < 8; db++) {
        short8v vb = *(const short8v*)(Vs + (db * 16 + l16) * 32 +
                                       ((q ^ (l16 & 3)) * 8));
        oacc[db] = mfma_bf16(pa8, vb, oacc[db]);
      }
    }
  }

  float lf = lp;
  lf += __shfl_xor(lf, 16);
  lf += __shfl_xor(lf, 32);
  float li[4];
#pragma unroll
  for (int rg = 0; rg < 4; rg++) li[rg] = 1.0f / __shfl(lf, q * 4 + rg);

  // ---- epilogue: O (C-layout) -> LDS transpose -> packed A-fragments ----
  __syncthreads();                     // all waves done reading staging LDS
  unsigned short* T = SM + wv * 16 * 136;   // per-wave [16 s][136 d]
#pragma unroll
  for (int rg = 0; rg < 4; rg++)
#pragma unroll
    for (int db = 0; db < 8; db++)
      T[(q * 4 + rg) * 136 + db * 16 + l16] = f2bf(oacc[db][rg] * li[rg]);
  // wave-private region; same-wave LDS ops are ordered -> no barrier
  const int mtile = (bi * cS + q0w) >> 4;
#pragma unroll
  for (int kbl = 0; kbl < 4; kbl++) {
    short8v fr = *(const short8v*)(T + l16 * 136 + kbl * 32 + q * 8);
    *(short8v*)(AOp + ((size_t)mtile * 64 + h * 4 + kbl) * 512 + lane * 8) = fr;
  }
}

// --------------------------- launch ----------------------------------------
extern "C" void kernel_launch(void* const* d_in, const int* in_sizes, int n_in,
                              void* d_out, int out_size, void* d_ws, size_t ws_size,
                              hipStream_t stream) {
  (void)in_sizes; (void)n_in; (void)out_size; (void)ws_size;
  char* ws = (char*)d_ws;
  size_t off = 0;
  auto alloc = [&](size_t bytes) -> char* {
    char* p = ws + off;
    off += (bytes + 255) & ~((size_t)255);
    return p;
  };
  int* flag            = (int*)alloc(256);
  float2* ropetab      = (float2*)alloc((size_t)cS * 64 * 8);
  float* nw            = (float*)alloc(256 * 4);
  float* scat          = (float*)alloc(4096 * 4);
  float* so            = (float*)alloc(2048 * 4);
  unsigned short* xp   = (unsigned short*)alloc((size_t)cM * cD * 2);
  unsigned short* wp   = (unsigned short*)alloc((size_t)cNqkv * cD * 2);
  unsigned short* wop  = (unsigned short*)alloc((size_t)cD * cH * cHD * 2);
  unsigned short* Qb   = (unsigned short*)alloc((size_t)cB * cH * cS * cHD * 2);
  unsigned short* Kb   = (unsigned short*)alloc((size_t)cB * cKVH * cS * cHD * 2);
  unsigned short* Vt   = (unsigned short*)alloc((size_t)cB * cKVH * cHD * cS * 2);
  unsigned short* AOp  = (unsigned short*)alloc((size_t)cM * cD * 2);

  detect_dtype<<<1, 256, 0, stream>>>((const unsigned*)d_in[0], flag);
  prep<<<537, 256, 0, stream>>>(d_in[9], d_in[10], d_in[2], d_in[4], d_in[6],
                                d_in[8], d_in[11], d_in[12], nw, scat, so,
                                ropetab, flag);
  pack_all<<<dim3(640, 8), 256, 0, stream>>>(
      d_in[0], (const int*)d_in[1], (const int*)d_in[3], (const int*)d_in[5],
      (const int*)d_in[7], xp, wp, wop, flag);

  gemm_qkv<<<dim3(cNqkv / 128, cM / 128), 256, 0, stream>>>(
      xp, wp, scat, ropetab, nw, Qb, Kb, Vt);
  attn<<<dim3(cS / 64, cH, cB), 256, 0, stream>>>(Qb, Kb, Vt, AOp);
  gemm_out<<<dim3(cD / 128, cM / 128), 256, 0, stream>>>(
      AOp, wop, so, d_out, flag, cD, (cH * cHD) / 32);
}

// Round 10
// 389.885 us; speedup vs baseline: 1.1346x; 1.0159x over previous
//
#include <hip/hip_runtime.h>

// ---------------------------------------------------------------------------
// QuantizedAttention: x[B,S,D] -> QKV proj (int8-quant wts) -> RMSNorm -> RoPE
//   -> causal GQA attention -> O proj.  B=2 S=2048 D=2048 H=16 KVH=8 HD=128.
// R17: R16 + LDS-free pack_all.  The fragment repack is a pure per-thread
// gather of 8 CONTIGUOUS source elements -> load float4x2 / int4x2 / ushort8
// directly, convert, store ushort8.  No LDS, no barriers (was: scalar loads
// + LDS round-trip + 2 syncs per block = ~5x off roofline).  Everything else
// byte-identical to R16 (detect_dtype dispatch kept; cores proven).
// ---------------------------------------------------------------------------

typedef __attribute__((ext_vector_type(4))) float floatx4;
typedef __attribute__((ext_vector_type(8))) short short8v;
typedef __attribute__((ext_vector_type(4))) short short4v;
typedef __attribute__((ext_vector_type(8))) unsigned short ushort8v;

#define DEVINL __device__ __forceinline__

constexpr int cB = 2, cS = 2048, cD = 2048, cH = 16, cKVH = 8, cHD = 128;
constexpr int cM = cB * cS;
constexpr int cNqkv = (cH + 2 * cKVH) * cHD;
constexpr float cEPS = 1e-6f;
// 1/sqrt(HD) * log2(e): softmax in base-2 domain (same softmax value).
constexpr float cSCL2 = 0.08838834764831845f * 1.4426950408889634f;

DEVINL unsigned short f2bf(float f) {
  unsigned u = __float_as_uint(f);
  unsigned r = ((u >> 16) & 1u) + 0x7FFFu;
  return (unsigned short)((u + r) >> 16);
}
DEVINL float bf2f(unsigned short h) { return __uint_as_float(((unsigned)h) << 16); }

DEVINL floatx4 mfma_bf16(short8v a, short8v b, floatx4 c) {
  return __builtin_amdgcn_mfma_f32_16x16x32_bf16(a, b, c, 0, 0, 0);
}

DEVINL void gl_lds16(const void* g, void* l) {
  __builtin_amdgcn_global_load_lds(
      (const __attribute__((address_space(1))) void*)g,
      (__attribute__((address_space(3))) void*)l, 16, 0, 0);
}

// --------------------------- dtype detection -------------------------------
__global__ void detect_dtype(const unsigned* __restrict__ x, int* __restrict__ flag) {
  __shared__ int cnt;
  if (threadIdx.x == 0) cnt = 0;
  __syncthreads();
  int c = 0;
  for (int i = threadIdx.x; i < 4096; i += 256) {
    unsigned e = (x[i] >> 7) & 0xFFu;
    c += (e >= 100u && e <= 142u) ? 1 : 0;
  }
  atomicAdd(&cnt, c);
  __syncthreads();
  if (threadIdx.x == 0) *flag = (cnt > 2457) ? 1 : 0;  // 1 = host is bf16
}

// -------------- merged small conversions + RoPE table (prep) ---------------
// blocks 0..24: conv_small body; blocks 25..536: rope_pack body.
__global__ void prep(const void* p9, const void* p10, const void* p2,
                     const void* p4, const void* p6, const void* p8,
                     const void* __restrict__ cosc, const void* __restrict__ sinc,
                     float* __restrict__ nw, float* __restrict__ scat,
                     float* __restrict__ so, float2* __restrict__ tab,
                     const int* __restrict__ flag) {
  const int b = (int)blockIdx.x;
  int f = *flag;
  auto rd = [&](const void* p, int idx) -> float {
    return f ? bf2f(((const unsigned short*)p)[idx]) : ((const float*)p)[idx];
  };
  if (b < 25) {
    int i = b * 256 + threadIdx.x;
    if (i < 256) {
      nw[i] = (i < 128) ? rd(p9, i) : rd(p10, i - 128);
    } else if (i < 256 + 4096) {
      int j = i - 256;
      scat[j] = (j < 2048) ? rd(p2, j) : (j < 3072 ? rd(p4, j - 2048) : rd(p6, j - 3072));
    } else if (i < 256 + 4096 + 2048) {
      int j = i - 4352;
      so[j] = rd(p8, j);
    }
  } else {
    int i = (b - 25) * 256 + threadIdx.x;
    if (i >= cS * 64) return;
    int s = i >> 6, t = i & 63;
    float c = f ? bf2f(((const unsigned short*)cosc)[s * cHD + t])
                : ((const float*)cosc)[s * cHD + t];
    float sn = f ? bf2f(((const unsigned short*)sinc)[s * cHD + t])
                 : ((const float*)sinc)[s * cHD + t];
    tab[i] = make_float2(c, sn);
  }
}

// --------------------- LDS-free vectorized fragment packer -----------------
// Fragment layout: dst[(T*64 + kb)*512 + lane*8 + j] =
//   src[T*16 + (lane&15)][kb*32 + (lane>>4)*8 + j]
// The 8 source elements per output ushort8 are CONTIGUOUS -> direct
// vector load + convert + store; no LDS, no barriers.
// bx<256: x -> xp (flag-selected dtype); bx in [256,512): wq/wk/wv -> wp;
// bx in [512,640): wo -> wop.
__global__ __launch_bounds__(256) void pack_all(
    const void* __restrict__ x, const int* __restrict__ wq,
    const int* __restrict__ wk, const int* __restrict__ wv,
    const int* __restrict__ wo, unsigned short* __restrict__ xp,
    unsigned short* __restrict__ wp, unsigned short* __restrict__ wop,
    const int* __restrict__ flag) {
  const int bx = (int)blockIdx.x, kc = (int)blockIdx.y, tid = threadIdx.x;
  const int lane = tid & 63, w = tid >> 6;
  const int q = lane >> 4, l16 = lane & 15;
  const void* src;
  unsigned short* dst;
  int Trow, Tdst, md;
  if (bx < 256) {
    src = x; dst = xp; md = (*flag) ? 3 : 1; Trow = bx; Tdst = bx;
  } else if (bx < 512) {
    int T = bx - 256;
    dst = wp; md = 2; Tdst = T;
    if (T < 128)      { src = wq; Trow = T; }
    else if (T < 192) { src = wk; Trow = T - 128; }
    else              { src = wv; Trow = T - 192; }
  } else {
    int T = bx - 512;
    src = wo; dst = wop; md = 2; Trow = T; Tdst = T;
  }
  const size_t rowb = (size_t)(Trow * 16 + l16) * 2048;
#pragma unroll
  for (int p = 0; p < 2; p++) {
    int kbl = w + p * 4;
    size_t idx = rowb + kc * 256 + kbl * 32 + q * 8;   // 8 contiguous elems
    ushort8v o;
    if (md == 1) {
      float4 v0 = ((const float4*)((const float*)src + idx))[0];
      float4 v1 = ((const float4*)((const float*)src + idx))[1];
      o[0] = f2bf(v0.x); o[1] = f2bf(v0.y); o[2] = f2bf(v0.z); o[3] = f2bf(v0.w);
      o[4] = f2bf(v1.x); o[5] = f2bf(v1.y); o[6] = f2bf(v1.z); o[7] = f2bf(v1.w);
    } else if (md == 2) {
      int4 v0 = ((const int4*)((const int*)src + idx))[0];
      int4 v1 = ((const int4*)((const int*)src + idx))[1];
      o[0] = f2bf((float)v0.x); o[1] = f2bf((float)v0.y);
      o[2] = f2bf((float)v0.z); o[3] = f2bf((float)v0.w);
      o[4] = f2bf((float)v1.x); o[5] = f2bf((float)v1.y);
      o[6] = f2bf((float)v1.z); o[7] = f2bf((float)v1.w);
    } else {
      // host already bf16: f2bf(bf2f(h)) == h exactly -> passthrough
      o = *(const ushort8v*)((const unsigned short*)src + idx);
    }
    *(ushort8v*)(dst + ((size_t)Tdst * 64 + kc * 8 + kbl) * 512 + lane * 8) = o;
  }
}

// --------------------- 4-phase register-streaming GEMM core ----------------
// Wave computes 64x64 (4x4 of 16x16x32 MFMA). 4 k-phases in flight (32
// outstanding global loads/wave) to cover L2 latency; no LDS, no barriers.
DEVINL void gemm_core4(const unsigned short* __restrict__ Ap,
                       const unsigned short* __restrict__ Bp,
                       int tm0, int tn0, int nkb, int lane,
                       floatx4 acc[4][4]) {
  const unsigned short* ap[4];
  const unsigned short* bp[4];
#pragma unroll
  for (int i = 0; i < 4; i++) {
    ap[i] = Ap + ((size_t)(tm0 + i) * 64) * 512 + lane * 8;
    bp[i] = Bp + ((size_t)(tn0 + i) * 64) * 512 + lane * 8;
  }
  short8v a[4][4], b[4][4];
#pragma unroll
  for (int p = 0; p < 4; p++)
#pragma unroll
    for (int i = 0; i < 4; i++) {
      a[p][i] = *(const short8v*)(ap[i] + p * 512);
      b[p][i] = *(const short8v*)(bp[i] + p * 512);
    }
  for (int kb = 0; kb < nkb; kb += 4) {
    const bool more = (kb + 4) < nkb;
#pragma unroll
    for (int p = 0; p < 4; p++) {
#pragma unroll
      for (int mt = 0; mt < 4; mt++)
#pragma unroll
        for (int nt = 0; nt < 4; nt++)
          acc[mt][nt] = mfma_bf16(a[p][mt], b[p][nt], acc[mt][nt]);
      if (more) {
        const int o = (kb + 4 + p) * 512;
#pragma unroll
        for (int i = 0; i < 4; i++) {
          a[p][i] = *(const short8v*)(ap[i] + o);
          b[p][i] = *(const short8v*)(bp[i] + o);
        }
      }
    }
  }
}

// ------------------- fused QKV GEMM + RMSNorm + RoPE + V^T -----------------
__global__ __launch_bounds__(256) void gemm_qkv(
    const unsigned short* __restrict__ Ap, const unsigned short* __restrict__ Bp,
    const float* __restrict__ colscale, const float2* __restrict__ ropetab,
    const float* __restrict__ nw, unsigned short* __restrict__ Qb,
    unsigned short* __restrict__ Kb, unsigned short* __restrict__ Vt) {
  __shared__ float4 smem4[2192];            // 35072 B (epilogue only)
  char* smem = (char*)smem4;
  const int tid = threadIdx.x;
  const int lane = tid & 63, wave = tid >> 6;
  const int q = lane >> 4, l16 = lane & 15;
  const int m0 = blockIdx.y * 128, n0 = blockIdx.x * 128;
  const int wm = (wave & 1) * 64, wn = (wave >> 1) * 64;

  floatx4 acc[4][4] = {};
  gemm_core4(Ap, Bp, (m0 + wm) >> 4, (n0 + wn) >> 4, cD / 32, lane, acc);

  float sc[4];
#pragma unroll
  for (int nt = 0; nt < 4; nt++) sc[nt] = colscale[n0 + wn + nt * 16 + l16];
#pragma unroll
  for (int mt = 0; mt < 4; mt++)
#pragma unroll
    for (int nt = 0; nt < 4; nt++)
#pragma unroll
      for (int rg = 0; rg < 4; rg++) acc[mt][nt][rg] *= sc[nt];

  const int tile_n = blockIdx.x;
  const int bi = m0 >> 11, sbase = m0 & (cS - 1);

  if (tile_n >= 24) {
    // V: transpose through LDS, store Vt[.,d,s]
    unsigned short* T = (unsigned short*)smem;   // [128 d][136 s]
#pragma unroll
    for (int mt = 0; mt < 4; mt++)
#pragma unroll
      for (int nt = 0; nt < 4; nt++) {
        short4v pk;
#pragma unroll
        for (int rg = 0; rg < 4; rg++) pk[rg] = (short)f2bf(acc[mt][nt][rg]);
        *(short4v*)(T + (wn + nt * 16 + l16) * 136 + (wm + mt * 16 + q * 4)) = pk;
      }
    __syncthreads();
    const int d = tid >> 1, sh = (tid & 1) * 64;
    unsigned short* dst = Vt + ((size_t)(bi * cKVH + (tile_n - 24)) * cHD + d) * cS
                          + sbase + sh;
#pragma unroll
    for (int j = 0; j < 8; j++)
      *(ushort8v*)(dst + j * 8) = *(const ushort8v*)(T + d * 136 + sh + j * 8);
  } else {
    // Q/K: RMSNorm + RoPE
    unsigned short* W = (unsigned short*)smem;   // 4 waves x 4096 ushorts
    float* ssq  = (float*)(smem + 32768);        // [2][128]
    float* invs = (float*)(smem + 33792);        // [128]

    float sl[4][4];
#pragma unroll
    for (int mt = 0; mt < 4; mt++)
#pragma unroll
      for (int rg = 0; rg < 4; rg++) {
        float s = 0.f;
#pragma unroll
        for (int nt = 0; nt < 4; nt++) s += acc[mt][nt][rg] * acc[mt][nt][rg];
        s += __shfl_xor(s, 1); s += __shfl_xor(s, 2);
        s += __shfl_xor(s, 4); s += __shfl_xor(s, 8);
        sl[mt][rg] = s;
      }
    unsigned short* Wo = W + wave * 4096;
#pragma unroll
    for (int mt = 0; mt < 4; mt++)
#pragma unroll
      for (int nt = 0; nt < 4; nt++) {
        short4v pk;
#pragma unroll
        for (int rg = 0; rg < 4; rg++) pk[rg] = (short)f2bf(acc[mt][nt][rg]);
        *(short4v*)(Wo + (mt * 4 + nt) * 256 + lane * 4) = pk;
      }
    if (l16 == 0) {
#pragma unroll
      for (int mt = 0; mt < 4; mt++)
#pragma unroll
        for (int rg = 0; rg < 4; rg++)
          ssq[((wave >> 1) & 1) * 128 + wm + mt * 16 + q * 4 + rg] = sl[mt][rg];
    }
    __syncthreads();
    if (tid < 128)
      invs[tid] = rsqrtf((ssq[tid] + ssq[128 + tid]) * (1.0f / cHD) + cEPS);
    __syncthreads();

    const unsigned short* Wp = W + (wave ^ 2) * 4096;
    const int wn1 = wave >> 1;
    const float* nwb = nw + (tile_n < 16 ? 0 : cHD);
    float wown[4], wpar[4];
#pragma unroll
    for (int nt = 0; nt < 4; nt++) {
      wown[nt] = nwb[wn1 * 64 + nt * 16 + l16];
      wpar[nt] = nwb[(wn1 ^ 1) * 64 + nt * 16 + l16];
    }
    unsigned short* dstb = (tile_n < 16)
        ? Qb + ((size_t)(bi * cH + tile_n) * cS) * cHD
        : Kb + ((size_t)(bi * cKVH + (tile_n - 16)) * cS) * cHD;
#pragma unroll
    for (int mt = 0; mt < 4; mt++) {
      float iv[4];
#pragma unroll
      for (int rg = 0; rg < 4; rg++) iv[rg] = invs[wm + mt * 16 + q * 4 + rg];
#pragma unroll
      for (int nt = 0; nt < 4; nt++) {
        short4v pk = *(const short4v*)(Wp + (mt * 4 + nt) * 256 + lane * 4);
#pragma unroll
        for (int rg = 0; rg < 4; rg++) {
          int srow = sbase + wm + mt * 16 + q * 4 + rg;
          float2 cs = ropetab[srow * 64 + nt * 16 + l16];
          float nown = acc[mt][nt][rg] * iv[rg] * wown[nt];
          float npar = bf2f((unsigned short)pk[rg]) * iv[rg] * wpar[nt];
          float o = wn1 == 0 ? nown * cs.x - npar * cs.y
                             : nown * cs.x + npar * cs.y;
          dstb[(size_t)srow * cHD + wn1 * 64 + nt * 16 + l16] = f2bf(o);
        }
      }
    }
  }
}

// ------------------- O-proj GEMM with fused flag-output --------------------
__global__ __launch_bounds__(256) void gemm_out(
    const unsigned short* __restrict__ Ap, const unsigned short* __restrict__ Bp,
    const float* __restrict__ colscale, void* __restrict__ Cout,
    const int* __restrict__ flag, int N, int nkb) {
  const int tid = threadIdx.x;
  const int lane = tid & 63, wave = tid >> 6;
  const int q = lane >> 4, l16 = lane & 15;
  const int m0 = blockIdx.y * 128, n0 = blockIdx.x * 128;
  const int wm = (wave & 1) * 64, wn = (wave >> 1) * 64;

  floatx4 acc[4][4] = {};
  gemm_core4(Ap, Bp, (m0 + wm) >> 4, (n0 + wn) >> 4, nkb, lane, acc);

  const int f = *flag;
#pragma unroll
  for (int mt = 0; mt < 4; mt++) {
    int r0 = m0 + wm + mt * 16 + q * 4;
#pragma unroll
    for (int nt = 0; nt < 4; nt++) {
      int cn = n0 + wn + nt * 16 + l16;
      float sc = colscale[cn];
#pragma unroll
      for (int rg = 0; rg < 4; rg++) {
        float v = acc[mt][nt][rg] * sc;
        if (f) ((unsigned short*)Cout)[(size_t)(r0 + rg) * N + cn] = f2bf(v);
        else   ((float*)Cout)[(size_t)(r0 + rg) * N + cn] = v;
      }
    }
  }
}

// --------------------------- flash attention (R9, unchanged) ---------------
// q-split waves (16 q rows/wave, 64/block).  32-kv windows, K tile [32][128]
// + V tile [128][32] both double-buffered in 32KB LDS -> 4 blocks/CU.
// K staged with sigma row-permutation (P values form K=32 MFMA A-fragments
// directly) + chunk XOR swizzle; V staged [d][kv] with kv-chunk XOR swizzle
// by (d&3).  All swizzles applied on the *global source* address (linear
// global_load_lds dest) and reproduced on the LDS read side.
// No-max softmax in exp2 domain; epilogue emits O-proj A-fragments.
__global__ __launch_bounds__(256, 4) void attn(
    const unsigned short* __restrict__ Qb, const unsigned short* __restrict__ Kb,
    const unsigned short* __restrict__ Vt, unsigned short* __restrict__ AOp) {
  __shared__ unsigned short SM[16384];       // 32 KB: (K 8KB + V 8KB) x2 bufs
  const int tid = threadIdx.x;
  const int lane = tid & 63, wv = tid >> 6;
  const int q = lane >> 4, l16 = lane & 15;
  const int bi = blockIdx.z, h = blockIdx.y;
  const int kh = h >> 1;
  const int bx = (int)blockIdx.x;
  // paired mapping: blocks (2i,2i+1) -> qt {i, 31-i}; each consecutive pair
  // is constant total work (one-round residency: 1024 blocks = 4/CU exactly).
  const int qt = (bx & 1) ? (31 - (bx >> 1)) : (bx >> 1);
  const int q0 = qt * 64;
  const int q0w = q0 + wv * 16;

  const unsigned short* Qbase = Qb + ((size_t)(bi * cH + h) * cS + q0w) * cHD;
  const unsigned short* Kbase = Kb + ((size_t)(bi * cKVH + kh) * cS) * cHD;
  const unsigned short* Vbase = Vt + ((size_t)(bi * cKVH + kh) * cHD) * cS;

  short8v qa[4];
#pragma unroll
  for (int c = 0; c < 4; c++)
    qa[c] = *(const short8v*)(Qbase + (size_t)l16 * cHD + c * 32 + q * 8);

  floatx4 oacc[8] = {};
  float lp = 0.f;

  // K staging source offsets: LDS visible row r (0..31) holds K[kv0+sig(r)],
  // stored chunk u holds source HD-chunk u^(r&15).
  int koff[2];
#pragma unroll
  for (int i = 0; i < 2; i++) {
    int s = (wv * 2 + i) * 64 + lane;
    int r = s >> 4, u = (s & 15) ^ (r & 15);
    int sig = ((r >> 2) & 3) * 8 + ((r >> 4) & 1) * 4 + (r & 3);
    koff[i] = sig * cHD + u * 8;
  }
  // V staging source offsets: LDS [128 d][32 kv]; row d stored kv-chunk c
  // holds source kv-chunk c^(d&3).
  int voff[2];
#pragma unroll
  for (int i = 0; i < 2; i++) {
    int s = (wv * 2 + i) * 64 + lane;
    int d = s >> 2, c2 = (s & 3) ^ (d & 3);
    voff[i] = d * cS + c2 * 8;
  }

  const int nwin = 2 * qt + 2;
  auto stage = [&](int win) {
    const int buf = (win & 1) * 8192;
    const int kv0 = win * 32;
    unsigned short* Kdst = SM + buf + (wv * 2) * 512;
    unsigned short* Vdst = SM + buf + 4096 + (wv * 2) * 512;
#pragma unroll
    for (int i = 0; i < 2; i++)
      gl_lds16(Kbase + (size_t)kv0 * cHD + koff[i], Kdst + i * 512);
#pragma unroll
    for (int i = 0; i < 2; i++)
      gl_lds16(Vbase + (size_t)kv0 + voff[i], Vdst + i * 512);
  };

  stage(0);
  for (int win = 0; win < nwin; win++) {
    __syncthreads();
    if (win + 1 < nwin) stage(win + 1);
    const int kv0 = win * 32;
    if (kv0 <= q0w + 15) {            // wave-uniform: window intersects rows
      const unsigned short* Ks = SM + (win & 1) * 8192;
      const unsigned short* Vs = Ks + 4096;

      floatx4 sres[2] = {};
#pragma unroll
      for (int c = 0; c < 4; c++) {
        short8v kf[2];
#pragma unroll
        for (int ntk = 0; ntk < 2; ntk++)
          kf[ntk] = *(const short8v*)(Ks + (ntk * 16 + l16) * 128 +
                                      (((c * 4 + q) ^ l16) * 8));
#pragma unroll
        for (int ntk = 0; ntk < 2; ntk++)
          sres[ntk] = mfma_bf16(kf[ntk], qa[c], sres[ntk]);
      }

      const bool maskw = (kv0 + 31 > q0w);
      short8v pa8;
#pragma unroll
      for (int ntk = 0; ntk < 2; ntk++) {
#pragma unroll
        for (int rg = 0; rg < 4; rg++) {
          float e = exp2f(sres[ntk][rg] * cSCL2);
          if (maskw) {
            // actual kv of visible slot (ntk,q,rg) under sigma; q row = l16
            int kvloc = q * 8 + ntk * 4 + rg;
            if (kv0 + kvloc > q0w + l16) e = 0.f;
          }
          lp += e;
          pa8[ntk * 4 + rg] = (short)f2bf(e);
        }
      }

#pragma unroll
      for (int db = 0; db < 8; db++) {
        short8v vb = *(const short8v*)(Vs + (db * 16 + l16) * 32 +
                                       ((q ^ (l16 & 3)) * 8));
        oacc[db] = mfma_bf16(pa8, vb, oacc[db]);
      }
    }
  }

  float lf = lp;
  lf += __shfl_xor(lf, 16);
  lf += __shfl_xor(lf, 32);
  float li[4];
#pragma unroll
  for (int rg = 0; rg < 4; rg++) li[rg] = 1.0f / __shfl(lf, q * 4 + rg);

  // ---- epilogue: O (C-layout) -> LDS transpose -> packed A-fragments ----
  __syncthreads();                     // all waves done reading staging LDS
  unsigned short* T = SM + wv * 16 * 136;   // per-wave [16 s][136 d]
#pragma unroll
  for (int rg = 0; rg < 4; rg++)
#pragma unroll
    for (int db = 0; db < 8; db++)
      T[(q * 4 + rg) * 136 + db * 16 + l16] = f2bf(oacc[db][rg] * li[rg]);
  // wave-private region; same-wave LDS ops are ordered -> no barrier
  const int mtile = (bi * cS + q0w) >> 4;
#pragma unroll
  for (int kbl = 0; kbl < 4; kbl++) {
    short8v fr = *(const short8v*)(T + l16 * 136 + kbl * 32 + q * 8);
    *(short8v*)(AOp + ((size_t)mtile * 64 + h * 4 + kbl) * 512 + lane * 8) = fr;
  }
}

// --------------------------- launch ----------------------------------------
extern "C" void kernel_launch(void* const* d_in, const int* in_sizes, int n_in,
                              void* d_out, int out_size, void* d_ws, size_t ws_size,
                              hipStream_t stream) {
  (void)in_sizes; (void)n_in; (void)out_size; (void)ws_size;
  char* ws = (char*)d_ws;
  size_t off = 0;
  auto alloc = [&](size_t bytes) -> char* {
    char* p = ws + off;
    off += (bytes + 255) & ~((size_t)255);
    return p;
  };
  int* flag            = (int*)alloc(256);
  float2* ropetab      = (float2*)alloc((size_t)cS * 64 * 8);
  float* nw            = (float*)alloc(256 * 4);
  float* scat          = (float*)alloc(4096 * 4);
  float* so            = (float*)alloc(2048 * 4);
  unsigned short* xp   = (unsigned short*)alloc((size_t)cM * cD * 2);
  unsigned short* wp   = (unsigned short*)alloc((size_t)cNqkv * cD * 2);
  unsigned short* wop  = (unsigned short*)alloc((size_t)cD * cH * cHD * 2);
  unsigned short* Qb   = (unsigned short*)alloc((size_t)cB * cH * cS * cHD * 2);
  unsigned short* Kb   = (unsigned short*)alloc((size_t)cB * cKVH * cS * cHD * 2);
  unsigned short* Vt   = (unsigned short*)alloc((size_t)cB * cKVH * cHD * cS * 2);
  unsigned short* AOp  = (unsigned short*)alloc((size_t)cM * cD * 2);

  detect_dtype<<<1, 256, 0, stream>>>((const unsigned*)d_in[0], flag);
  prep<<<537, 256, 0, stream>>>(d_in[9], d_in[10], d_in[2], d_in[4], d_in[6],
                                d_in[8], d_in[11], d_in[12], nw, scat, so,
                                ropetab, flag);
  pack_all<<<dim3(640, 8), 256, 0, stream>>>(
      d_in[0], (const int*)d_in[1], (const int*)d_in[3], (const int*)d_in[5],
      (const int*)d_in[7], xp, wp, wop, flag);

  gemm_qkv<<<dim3(cNqkv / 128, cM / 128), 256, 0, stream>>>(
      xp, wp, scat, ropetab, nw, Qb, Kb, Vt);
  attn<<<dim3(cS / 64, cH, cB), 256, 0, stream>>>(Qb, Kb, Vt, AOp);
  gemm_out<<<dim3(cD / 128, cM / 128), 256, 0, stream>>>(
      AOp, wop, so, d_out, flag, cD, (cH * cHD) / 32);
}